// Round 1
// baseline (7608.480 us; speedup 1.0000x reference)
//
#include <hip/hip_runtime.h>

#define NN 10000
#define EE 160000
#define ECH 80000
#define CC 128
#define NEL 10
#define NGR 16

static inline int cdiv(int a, int b) { return (a + b - 1) / b; }

__device__ __forceinline__ float silu_f(float x) { return x / (1.0f + __expf(-x)); }

// ---------------------------------------------------------------------------
// Generic row-GEMM: out[r][c] = sum_k in[r][k] * W[k][c]   (W row-major, w_ld)
// MODE 0: store  1: store+silu  6: store-accumulate (out +=)
// MODE 2: atomicAdd accS[rcv[e]*128+c] += val * gA[snd[e]*128+c]
// MODE 3: atomicAdd accS[rcv[e]*128+c] += val * dot_d(gA[snd*384+d*128+c]*Yv[e][d]) / sqrt3
// MODE 4: atomicAdd accV[rcv*384+d*128+c] += val * gA[snd*128+c] * Yv[e][d]
// MODE 5: atomicAdd accV[rcv*384+d*128+c] += val * gA[snd*384+d*128+c]
// ---------------------------------------------------------------------------
template <int K, int N, int MODE>
__global__ __launch_bounds__(256) void rowgemm_k(
    const float* __restrict__ in, int in_ld,
    const float* __restrict__ W, int w_ld,
    float* __restrict__ out, int out_ld,
    int R, float scale,
    const int* __restrict__ snd, const int* __restrict__ rcv,
    const float* __restrict__ Yv,
    const float* __restrict__ gA,
    float* __restrict__ accS, float* __restrict__ accV)
{
    constexpr int TR = 8192 / N;     // rows per tile (64 for N=128, 128 for N=64)
    constexpr int CG = N / 8;        // col groups of 8
    constexpr int RG = 256 / CG;     // row groups of 4
    static_assert(RG * 4 == TR, "tile shape mismatch");
    constexpr int KC = (K < 64 ? K : 64);

    __shared__ float Wl[KC][N];
    __shared__ float inT[K][TR + 4];

    const int tid = threadIdx.x;
    const int cg = tid % CG, rg = tid / CG;
    const int c0 = cg * 8, r0 = rg * 4;
    const int row0 = blockIdx.x * TR;

    // stage input tile transposed: inT[k][r]
    for (int i = tid; i < K * TR; i += 256) {
        int r = i / K, k = i - r * K;
        int row = row0 + r;
        inT[k][r] = (row < R) ? in[row * in_ld + k] : 0.0f;
    }

    float acc[4][8];
#pragma unroll
    for (int i = 0; i < 4; ++i)
#pragma unroll
        for (int j = 0; j < 8; ++j) acc[i][j] = 0.0f;

    for (int kc = 0; kc < K; kc += KC) {
        __syncthreads();
        for (int i = tid; i < KC * N; i += 256) {
            int k = i / N, c = i - k * N;
            Wl[k][c] = W[(kc + k) * w_ld + c];
        }
        __syncthreads();
#pragma unroll 8
        for (int kk = 0; kk < KC; ++kk) {
            const float4 a  = *(const float4*)&inT[kc + kk][r0];
            const float4 b0 = *(const float4*)&Wl[kk][c0];
            const float4 b1 = *(const float4*)&Wl[kk][c0 + 4];
            const float av[4] = {a.x, a.y, a.z, a.w};
            const float bv[8] = {b0.x, b0.y, b0.z, b0.w, b1.x, b1.y, b1.z, b1.w};
#pragma unroll
            for (int i = 0; i < 4; ++i)
#pragma unroll
                for (int j = 0; j < 8; ++j)
                    acc[i][j] = fmaf(av[i], bv[j], acc[i][j]);
        }
    }

    if constexpr (MODE == 0 || MODE == 1 || MODE == 6) {
#pragma unroll
        for (int i = 0; i < 4; ++i) {
            int row = row0 + r0 + i;
            if (row >= R) break;
#pragma unroll
            for (int j = 0; j < 8; ++j) {
                float v = acc[i][j] * scale;
                if constexpr (MODE == 1) v = silu_f(v);
                int idx = row * out_ld + c0 + j;
                if constexpr (MODE == 6) out[idx] += v;
                else out[idx] = v;
            }
        }
    } else {
#pragma unroll
        for (int i = 0; i < 4; ++i) {
            int e = row0 + r0 + i;
            if (e >= R) break;
            int s = snd[e], rr = rcv[e];
            float y0 = 0.f, y1 = 0.f, y2 = 0.f;
            if constexpr (MODE == 3 || MODE == 4) {
                y0 = Yv[e * 3 + 0]; y1 = Yv[e * 3 + 1]; y2 = Yv[e * 3 + 2];
            }
#pragma unroll
            for (int j = 0; j < 8; ++j) {
                int c = c0 + j;
                float wv = acc[i][j];
                if constexpr (MODE == 2) {
                    atomicAdd(&accS[rr * CC + c], wv * gA[s * CC + c]);
                } else if constexpr (MODE == 3) {
                    const float* g = gA + s * 384;
                    float dv = g[c] * y0 + g[CC + c] * y1 + g[2 * CC + c] * y2;
                    atomicAdd(&accS[rr * CC + c], wv * dv * 0.57735026919f);
                } else if constexpr (MODE == 4) {
                    float t = wv * gA[s * CC + c];
                    atomicAdd(&accV[rr * 384 + c],          t * y0);
                    atomicAdd(&accV[rr * 384 + CC + c],     t * y1);
                    atomicAdd(&accV[rr * 384 + 2 * CC + c], t * y2);
                } else { // MODE 5
                    const float* g = gA + s * 384;
                    atomicAdd(&accV[rr * 384 + c],          wv * g[c]);
                    atomicAdd(&accV[rr * 384 + CC + c],     wv * g[CC + c]);
                    atomicAdd(&accV[rr * 384 + 2 * CC + c], wv * g[2 * CC + c]);
                }
            }
        }
    }
}

// ---------------------------------------------------------------------------
__global__ void k_geom(const float* __restrict__ pos, const float* __restrict__ shifts,
                       const int* __restrict__ snd, const int* __restrict__ rcv,
                       float* __restrict__ Yv, float* __restrict__ ef)
{
    int e = blockIdx.x * 256 + threadIdx.x;
    if (e >= EE) return;
    int s = snd[e], r = rcv[e];
    float vx = pos[r * 3 + 0] - pos[s * 3 + 0] + shifts[e * 3 + 0];
    float vy = pos[r * 3 + 1] - pos[s * 3 + 1] + shifts[e * 3 + 1];
    float vz = pos[r * 3 + 2] - pos[s * 3 + 2] + shifts[e * 3 + 2];
    float len = sqrtf(vx * vx + vy * vy + vz * vz + 1e-12f);
    float inv = 1.0f / len;
    const float SQ3 = 1.7320508075688772f;
    Yv[e * 3 + 0] = SQ3 * vx * inv;
    Yv[e * 3 + 1] = SQ3 * vy * inv;
    Yv[e * 3 + 2] = SQ3 * vz * inv;
    float u = len * 0.2f;
    float fc = 0.0f;
    if (u < 1.0f) {
        float u2 = u * u, u4 = u2 * u2, u5 = u4 * u, u6 = u5 * u, u7 = u6 * u;
        fc = 1.0f - 21.0f * u5 + 35.0f * u6 - 15.0f * u7;
    }
    float pref = 0.6324555320336759f * inv * fc;
    const float PIO5 = 0.6283185307179586f; // pi/5
#pragma unroll
    for (int n = 1; n <= 8; ++n)
        ef[e * 8 + n - 1] = pref * sinf((float)n * PIO5 * len);
}

__global__ void k_species(const float* __restrict__ attrs, int* __restrict__ species)
{
    int n = blockIdx.x * 256 + threadIdx.x;
    if (n >= NN) return;
    int sp = 0;
#pragma unroll
    for (int j = 0; j < NEL; ++j)
        if (attrs[n * NEL + j] > 0.5f) sp = j;
    species[n] = sp;
}

__global__ void k_embed(const float* __restrict__ W_emb, const int* __restrict__ species,
                        float* __restrict__ h)
{
    int t = blockIdx.x * 256 + threadIdx.x;
    if (t >= NN * CC) return;
    int n = t >> 7, c = t & 127;
    h[t] = W_emb[species[n] * CC + c];
}

__global__ void k_rmix(const float* __restrict__ Rmid, const float* __restrict__ Rout,
                       float* __restrict__ rmix)
{
    int c = threadIdx.x;
    float s = 0.f;
#pragma unroll
    for (int k = 0; k < 16; ++k) s = fmaf(Rmid[c * 16 + k], Rout[k], s);
    rmix[c] = s;
}

__global__ void k_B1(const int* __restrict__ species,
                     const float* __restrict__ As_l, const float* __restrict__ Av_l,
                     const float* __restrict__ P_s1, const float* __restrict__ P_ss,
                     const float* __restrict__ P_vv, const float* __restrict__ P_v1,
                     const float* __restrict__ P_sv,
                     float* __restrict__ Bs, float* __restrict__ Bv)
{
    int t = blockIdx.x * 256 + threadIdx.x;
    if (t >= NN * CC) return;
    int n = t >> 7, c = t & 127;
    int sp = species[n];
    int pb = sp * CC + c;
    int vb = n * 384 + c;
    float as = As_l[t];
    float a0 = Av_l[vb], a1 = Av_l[vb + CC], a2 = Av_l[vb + 2 * CC];
    Bs[t] = P_s1[pb] * as + P_ss[pb] * as * as
          + P_vv[pb] * (a0 * a0 + a1 * a1 + a2 * a2) * 0.57735026919f;
    float tv = P_v1[pb] + P_sv[pb] * as;
    Bv[vb] = tv * a0; Bv[vb + CC] = tv * a1; Bv[vb + 2 * CC] = tv * a2;
}

__global__ void k_B2(const int* __restrict__ species,
                     const float* __restrict__ As_l, const float* __restrict__ Av_l,
                     const float* __restrict__ P_v1, const float* __restrict__ P_sv,
                     float* __restrict__ Bv)
{
    int t = blockIdx.x * 256 + threadIdx.x;
    if (t >= NN * CC) return;
    int n = t >> 7, c = t & 127;
    int sp = species[n];
    int pb = sp * CC + c;
    int vb = n * 384 + c;
    float as = As_l[t];
    float tv = P_v1[pb] + P_sv[pb] * as;
    Bv[vb] = tv * Av_l[vb];
    Bv[vb + CC] = tv * Av_l[vb + CC];
    Bv[vb + 2 * CC] = tv * Av_l[vb + 2 * CC];
}

__global__ void k_dip1(const float* __restrict__ h_v, const float* __restrict__ R1,
                       float* __restrict__ dip1)
{
    int n = blockIdx.x, l = threadIdx.x;
    const float* hb = h_v + n * 384;
#pragma unroll
    for (int d = 0; d < 3; ++d) {
        float v = hb[d * CC + l] * R1[l] + hb[d * CC + 64 + l] * R1[64 + l];
        for (int o = 32; o > 0; o >>= 1) v += __shfl_down(v, o);
        if (l == 0) dip1[n * 3 + d] = v;
    }
}

__global__ void k_sc(const int* __restrict__ species, const float* __restrict__ h_v,
                     const float* __restrict__ Wsk, float* __restrict__ h2v)
{
    int n = blockIdx.x, f = threadIdx.x;
    int sp = species[n];
    const float* Wp = Wsk + sp * (CC * CC);
    const float* hvn = h_v + n * 384;
    float a0 = 0.f, a1 = 0.f, a2 = 0.f;
    for (int c = 0; c < CC; ++c) {
        float w = Wp[c * CC + f];
        a0 = fmaf(hvn[c], w, a0);
        a1 = fmaf(hvn[CC + c], w, a1);
        a2 = fmaf(hvn[2 * CC + c], w, a2);
    }
    h2v[n * 384 + f] = a0;
    h2v[n * 384 + CC + f] = a1;
    h2v[n * 384 + 2 * CC + f] = a2;
}

__global__ void k_final(const float* __restrict__ h2v, const float* __restrict__ rmix,
                        const float* __restrict__ dip1, const int* __restrict__ batch,
                        const float* __restrict__ charges, const float* __restrict__ pos,
                        float* __restrict__ out)
{
    int n = blockIdx.x, l = threadIdx.x;
    const float* hb = h2v + n * 384;
    float r0 = rmix[l], r1 = rmix[64 + l];
    float red[3];
#pragma unroll
    for (int d = 0; d < 3; ++d) {
        float v = hb[d * CC + l] * r0 + hb[d * CC + 64 + l] * r1;
        for (int o = 32; o > 0; o >>= 1) v += __shfl_down(v, o);
        red[d] = v;
    }
    if (l == 0) {
        int g = batch[n];
        float q = charges[n];
#pragma unroll
        for (int d = 0; d < 3; ++d) {
            float a = dip1[n * 3 + d] + 0.5f * red[d];
            out[48 + n * 3 + d] = a;
            atomicAdd(&out[g * 3 + d], a + q * pos[n * 3 + d]);
        }
    }
}

// ---------------------------------------------------------------------------
extern "C" void kernel_launch(void* const* d_in, const int* in_sizes, int n_in,
                              void* d_out, int out_size, void* d_ws, size_t ws_size,
                              hipStream_t stream)
{
    const float* positions = (const float*)d_in[0];
    const float* node_attrs = (const float*)d_in[1];
    const float* charges = (const float*)d_in[2];
    const float* shifts = (const float*)d_in[3];
    const int*   eidx = (const int*)d_in[4];
    const int*   batch = (const int*)d_in[5];
    const float* W_emb  = (const float*)d_in[7];
    const float* W_up1  = (const float*)d_in[8];
    const float* Wr1_1  = (const float*)d_in[9];
    const float* Wr1_2  = (const float*)d_in[10];
    const float* Wr1_3  = (const float*)d_in[11];
    const float* Wr1_o  = (const float*)d_in[12];
    const float* Wlin1_s = (const float*)d_in[13];
    const float* Wlin1_v = (const float*)d_in[14];
    const float* P1_s1 = (const float*)d_in[15];
    const float* P1_ss = (const float*)d_in[16];
    const float* P1_vv = (const float*)d_in[17];
    const float* P1_v1 = (const float*)d_in[18];
    const float* P1_sv = (const float*)d_in[19];
    const float* Lp1_s = (const float*)d_in[20];
    const float* Lp1_v = (const float*)d_in[21];
    const float* R1    = (const float*)d_in[22];
    const float* Wsk   = (const float*)d_in[23];
    const float* Wup2_s = (const float*)d_in[24];
    const float* Wup2_v = (const float*)d_in[25];
    const float* Wr2_1 = (const float*)d_in[26];
    const float* Wr2_2 = (const float*)d_in[27];
    const float* Wr2_3 = (const float*)d_in[28];
    const float* Wr2_o = (const float*)d_in[29];
    const float* Wlin2_s = (const float*)d_in[30];
    const float* Wlin2_v = (const float*)d_in[31];
    const float* P2_v1 = (const float*)d_in[32];
    const float* P2_sv = (const float*)d_in[33];
    const float* Lp2_v = (const float*)d_in[34];
    const float* Rmid  = (const float*)d_in[35];
    const float* Rout  = (const float*)d_in[36];
    (void)in_sizes; (void)n_in; (void)out_size; (void)ws_size;

    const int* snd = eidx;
    const int* rcv = eidx + EE;
    float* out = (float*)d_out;

    char* ws = (char*)d_ws;
    size_t off = 0;
    auto alloc = [&](size_t bytes) -> float* {
        float* p = (float*)(ws + off);
        off = (off + bytes + 255) & ~(size_t)255;
        return p;
    };
    int*   species = (int*)alloc((size_t)NN * 4);
    float* Yv   = alloc((size_t)EE * 3 * 4);
    float* ef   = alloc((size_t)EE * 8 * 4);
    float* A_s  = alloc((size_t)NN * CC * 4);       // also A2_s (A_v must follow!)
    float* A_v  = alloc((size_t)NN * 3 * CC * 4);   // also Bv / A2_v / B2v
    float* hbuf = alloc((size_t)NN * CC * 4);       // h -> Bs -> hs
    float* hu   = alloc((size_t)NN * CC * 4);       // hu -> h_s
    float* As_l = alloc((size_t)NN * CC * 4);
    float* Av_l = alloc((size_t)NN * 3 * CC * 4);
    float* h_v  = alloc((size_t)NN * 3 * CC * 4);   // layer-1 vector feats (kept for sc_v)
    float* hv   = alloc((size_t)NN * 3 * CC * 4);
    float* h2v  = alloc((size_t)NN * 3 * CC * 4);
    float* dip1 = alloc((size_t)NN * 3 * 4);
    float* rmix = alloc((size_t)CC * 4);
    float* hb1  = alloc((size_t)ECH * 64 * 4);
    float* hb2  = alloc((size_t)ECH * 64 * 4);

    const float inv16 = 1.0f / 16.0f;
    const float one = 1.0f;
    const int* ni = nullptr;
    const float* nf = nullptr;
    float* nfo = nullptr;

    hipMemsetAsync(d_out, 0, 48 * 4, stream);
    hipMemsetAsync(A_s, 0, (size_t)NN * 4 * CC * 4, stream);  // A_s + A_v together

    k_geom<<<cdiv(EE, 256), 256, 0, stream>>>(positions, shifts, snd, rcv, Yv, ef);
    k_species<<<cdiv(NN, 256), 256, 0, stream>>>(node_attrs, species);
    k_embed<<<cdiv(NN * CC, 256), 256, 0, stream>>>(W_emb, species, hbuf);
    k_rmix<<<1, CC, 0, stream>>>(Rmid, Rout, rmix);

    // hu = h @ W_up1
    rowgemm_k<128, 128, 0><<<cdiv(NN, 64), 256, 0, stream>>>(
        hbuf, 128, W_up1, 128, hu, 128, NN, one, ni, ni, nf, nf, nfo, nfo);

    // ---- layer 1 edge MLP + message scatter (2 chunks) ----
    for (int ch = 0; ch < 2; ++ch) {
        int eo = ch * ECH;
        const float* efc = ef + (size_t)eo * 8;
        const float* Yvc = Yv + (size_t)eo * 3;
        rowgemm_k<8, 64, 1><<<cdiv(ECH, 128), 256, 0, stream>>>(
            efc, 8, Wr1_1, 64, hb1, 64, ECH, one, ni, ni, nf, nf, nfo, nfo);
        rowgemm_k<64, 64, 1><<<cdiv(ECH, 128), 256, 0, stream>>>(
            hb1, 64, Wr1_2, 64, hb2, 64, ECH, one, ni, ni, nf, nf, nfo, nfo);
        rowgemm_k<64, 64, 1><<<cdiv(ECH, 128), 256, 0, stream>>>(
            hb2, 64, Wr1_3, 64, hb1, 64, ECH, one, ni, ni, nf, nf, nfo, nfo);
        rowgemm_k<64, 128, 2><<<cdiv(ECH, 64), 256, 0, stream>>>(
            hb1, 64, Wr1_o, 256, nfo, 0, ECH, one, snd + eo, rcv + eo, Yvc, hu, A_s, nfo);
        rowgemm_k<64, 128, 4><<<cdiv(ECH, 64), 256, 0, stream>>>(
            hb1, 64, Wr1_o + 128, 256, nfo, 0, ECH, one, snd + eo, rcv + eo, Yvc, hu, nfo, A_v);
    }

    // ---- layer 1 node side ----
    rowgemm_k<128, 128, 0><<<cdiv(NN, 64), 256, 0, stream>>>(
        A_s, 128, Wlin1_s, 128, As_l, 128, NN, inv16, ni, ni, nf, nf, nfo, nfo);
    rowgemm_k<128, 128, 0><<<cdiv(3 * NN, 64), 256, 0, stream>>>(
        A_v, 128, Wlin1_v, 128, Av_l, 128, 3 * NN, inv16, ni, ni, nf, nf, nfo, nfo);
    k_B1<<<cdiv(NN * CC, 256), 256, 0, stream>>>(
        species, As_l, Av_l, P1_s1, P1_ss, P1_vv, P1_v1, P1_sv, hbuf /*Bs*/, A_v /*Bv*/);
    rowgemm_k<128, 128, 0><<<cdiv(NN, 64), 256, 0, stream>>>(
        hbuf, 128, Lp1_s, 128, hu /*h_s*/, 128, NN, one, ni, ni, nf, nf, nfo, nfo);
    rowgemm_k<128, 128, 0><<<cdiv(3 * NN, 64), 256, 0, stream>>>(
        A_v /*Bv*/, 128, Lp1_v, 128, h_v, 128, 3 * NN, one, ni, ni, nf, nf, nfo, nfo);
    k_dip1<<<NN, 64, 0, stream>>>(h_v, R1, dip1);
    rowgemm_k<128, 128, 0><<<cdiv(NN, 64), 256, 0, stream>>>(
        hu /*h_s*/, 128, Wup2_s, 128, hbuf /*hs*/, 128, NN, one, ni, ni, nf, nf, nfo, nfo);
    rowgemm_k<128, 128, 0><<<cdiv(3 * NN, 64), 256, 0, stream>>>(
        h_v, 128, Wup2_v, 128, hv, 128, 3 * NN, one, ni, ni, nf, nf, nfo, nfo);

    // ---- layer 2 edge MLP + message scatter ----
    hipMemsetAsync(A_s, 0, (size_t)NN * 4 * CC * 4, stream);  // zero A2_s + A2_v
    for (int ch = 0; ch < 2; ++ch) {
        int eo = ch * ECH;
        const float* efc = ef + (size_t)eo * 8;
        const float* Yvc = Yv + (size_t)eo * 3;
        rowgemm_k<8, 64, 1><<<cdiv(ECH, 128), 256, 0, stream>>>(
            efc, 8, Wr2_1, 64, hb1, 64, ECH, one, ni, ni, nf, nf, nfo, nfo);
        rowgemm_k<64, 64, 1><<<cdiv(ECH, 128), 256, 0, stream>>>(
            hb1, 64, Wr2_2, 64, hb2, 64, ECH, one, ni, ni, nf, nf, nfo, nfo);
        rowgemm_k<64, 64, 1><<<cdiv(ECH, 128), 256, 0, stream>>>(
            hb2, 64, Wr2_3, 64, hb1, 64, ECH, one, ni, ni, nf, nf, nfo, nfo);
        rowgemm_k<64, 128, 2><<<cdiv(ECH, 64), 256, 0, stream>>>(
            hb1, 64, Wr2_o, 512, nfo, 0, ECH, one, snd + eo, rcv + eo, Yvc, hbuf /*hs*/, A_s, nfo);
        rowgemm_k<64, 128, 3><<<cdiv(ECH, 64), 256, 0, stream>>>(
            hb1, 64, Wr2_o + 128, 512, nfo, 0, ECH, one, snd + eo, rcv + eo, Yvc, hv, A_s, nfo);
        rowgemm_k<64, 128, 4><<<cdiv(ECH, 64), 256, 0, stream>>>(
            hb1, 64, Wr2_o + 256, 512, nfo, 0, ECH, one, snd + eo, rcv + eo, Yvc, hbuf /*hs*/, nfo, A_v);
        rowgemm_k<64, 128, 5><<<cdiv(ECH, 64), 256, 0, stream>>>(
            hb1, 64, Wr2_o + 384, 512, nfo, 0, ECH, one, snd + eo, rcv + eo, Yvc, hv, nfo, A_v);
    }

    // ---- layer 2 node side ----
    rowgemm_k<128, 128, 0><<<cdiv(NN, 64), 256, 0, stream>>>(
        A_s, 128, Wlin2_s, 128, As_l, 128, NN, inv16, ni, ni, nf, nf, nfo, nfo);
    rowgemm_k<128, 128, 0><<<cdiv(3 * NN, 64), 256, 0, stream>>>(
        A_v, 128, Wlin2_v, 128, Av_l, 128, 3 * NN, inv16, ni, ni, nf, nf, nfo, nfo);
    k_sc<<<NN, 128, 0, stream>>>(species, h_v, Wsk, h2v);
    k_B2<<<cdiv(NN * CC, 256), 256, 0, stream>>>(species, As_l, Av_l, P2_v1, P2_sv, A_v /*B2v*/);
    rowgemm_k<128, 128, 6><<<cdiv(3 * NN, 64), 256, 0, stream>>>(
        A_v /*B2v*/, 128, Lp2_v, 128, h2v, 128, 3 * NN, one, ni, ni, nf, nf, nfo, nfo);

    k_final<<<NN, 64, 0, stream>>>(h2v, rmix, dip1, batch, charges, positions, out);
}

// Round 2
// 1468.641 us; speedup vs baseline: 5.1806x; 5.1806x over previous
//
#include <hip/hip_runtime.h>

#define NN 10000
#define EE 160000
#define CC 128
#define NEL 10
#define NGR 16

static inline int cdiv(int a, int b) { return (a + b - 1) / b; }

__device__ __forceinline__ float silu_f(float x) { return x / (1.0f + __expf(-x)); }

// ---------------------------------------------------------------------------
// Generic row-GEMM: out[r][c] = sum_k in[r][k] * W[k][c]   (W row-major, w_ld)
// MODE 0: store   1: store+silu   6: out += (accumulate)
// Safe for in-place (out==in) since all global reads complete before stores.
// ---------------------------------------------------------------------------
template <int K, int N, int MODE>
__global__ __launch_bounds__(256) void rowgemm_k(
    const float* __restrict__ in, int in_ld,
    const float* __restrict__ W, int w_ld,
    float* __restrict__ out, int out_ld,
    int R, float scale)
{
    constexpr int TR = 8192 / N;     // rows per tile (64 for N=128, 128 for N=64)
    constexpr int CG = N / 8;        // col groups of 8
    constexpr int RG = 256 / CG;
    static_assert(RG * 4 == TR, "tile shape mismatch");
    constexpr int KC = (K < 64 ? K : 64);

    __shared__ float Wl[KC][N];
    __shared__ float inT[K][TR + 4];

    const int tid = threadIdx.x;
    const int cg = tid % CG, rg = tid / CG;
    const int c0 = cg * 8, r0 = rg * 4;
    const int row0 = blockIdx.x * TR;

    for (int i = tid; i < K * TR; i += 256) {
        int r = i / K, k = i - r * K;
        int row = row0 + r;
        inT[k][r] = (row < R) ? in[row * in_ld + k] : 0.0f;
    }

    float acc[4][8];
#pragma unroll
    for (int i = 0; i < 4; ++i)
#pragma unroll
        for (int j = 0; j < 8; ++j) acc[i][j] = 0.0f;

    for (int kc = 0; kc < K; kc += KC) {
        __syncthreads();
        for (int i = tid; i < KC * N; i += 256) {
            int k = i / N, c = i - k * N;
            Wl[k][c] = W[(kc + k) * w_ld + c];
        }
        __syncthreads();
#pragma unroll 8
        for (int kk = 0; kk < KC; ++kk) {
            const float4 a  = *(const float4*)&inT[kc + kk][r0];
            const float4 b0 = *(const float4*)&Wl[kk][c0];
            const float4 b1 = *(const float4*)&Wl[kk][c0 + 4];
            const float av[4] = {a.x, a.y, a.z, a.w};
            const float bv[8] = {b0.x, b0.y, b0.z, b0.w, b1.x, b1.y, b1.z, b1.w};
#pragma unroll
            for (int i = 0; i < 4; ++i)
#pragma unroll
                for (int j = 0; j < 8; ++j)
                    acc[i][j] = fmaf(av[i], bv[j], acc[i][j]);
        }
    }

#pragma unroll
    for (int i = 0; i < 4; ++i) {
        int row = row0 + r0 + i;
        if (row >= R) break;
#pragma unroll
        for (int j = 0; j < 8; ++j) {
            float v = acc[i][j] * scale;
            if constexpr (MODE == 1) v = silu_f(v);
            int idx = row * out_ld + c0 + j;
            if constexpr (MODE == 6) out[idx] += v;
            else out[idx] = v;
        }
    }
}

// ---------------------------------------------------------------------------
// CSR build
// ---------------------------------------------------------------------------
__global__ void k_count(const int* __restrict__ rcv, int* __restrict__ deg)
{
    int e = blockIdx.x * 256 + threadIdx.x;
    if (e < EE) atomicAdd(&deg[rcv[e]], 1);
}

__global__ __launch_bounds__(256) void k_scan(const int* __restrict__ deg,
                                              int* __restrict__ rowptr,
                                              int* __restrict__ cursor)
{
    __shared__ int part[256];
    const int t = threadIdx.x;
    const int PER = (NN + 255) / 256;   // 40
    int base = t * PER;
    int s = 0;
    for (int j = 0; j < PER; ++j) { int idx = base + j; if (idx < NN) s += deg[idx]; }
    part[t] = s;
    __syncthreads();
    for (int off = 1; off < 256; off <<= 1) {
        int v = (t >= off) ? part[t - off] : 0;
        __syncthreads();
        part[t] += v;
        __syncthreads();
    }
    int run = (t == 0) ? 0 : part[t - 1];
    for (int j = 0; j < PER; ++j) {
        int idx = base + j;
        if (idx < NN) { rowptr[idx] = run; cursor[idx] = run; run += deg[idx]; }
    }
    if (t == 255) rowptr[NN] = part[255];
}

__global__ void k_fill(const int* __restrict__ rcv, int* __restrict__ cursor,
                       int* __restrict__ perm)
{
    int e = blockIdx.x * 256 + threadIdx.x;
    if (e >= EE) return;
    int pos = atomicAdd(&cursor[rcv[e]], 1);
    perm[pos] = e;
}

__global__ void k_sortseg(const int* __restrict__ rowptr, int* __restrict__ perm)
{
    int n = blockIdx.x * 256 + threadIdx.x;
    if (n >= NN) return;
    int a = rowptr[n], b = rowptr[n + 1];
    for (int i = a + 1; i < b; ++i) {
        int v = perm[i];
        int j = i - 1;
        while (j >= a && perm[j] > v) { perm[j + 1] = perm[j]; --j; }
        perm[j + 1] = v;
    }
}

// geometry, written in CSR (permuted) edge order
__global__ void k_geom_perm(const float* __restrict__ pos, const float* __restrict__ shifts,
                            const int* __restrict__ snd, const int* __restrict__ rcv,
                            const int* __restrict__ perm,
                            float* __restrict__ Yv, float* __restrict__ ef,
                            int* __restrict__ psnd)
{
    int i = blockIdx.x * 256 + threadIdx.x;
    if (i >= EE) return;
    int e = perm[i];
    int s = snd[e], r = rcv[e];
    psnd[i] = s;
    float vx = pos[r * 3 + 0] - pos[s * 3 + 0] + shifts[e * 3 + 0];
    float vy = pos[r * 3 + 1] - pos[s * 3 + 1] + shifts[e * 3 + 1];
    float vz = pos[r * 3 + 2] - pos[s * 3 + 2] + shifts[e * 3 + 2];
    float len = sqrtf(vx * vx + vy * vy + vz * vz + 1e-12f);
    float inv = 1.0f / len;
    const float SQ3 = 1.7320508075688772f;
    Yv[i * 3 + 0] = SQ3 * vx * inv;
    Yv[i * 3 + 1] = SQ3 * vy * inv;
    Yv[i * 3 + 2] = SQ3 * vz * inv;
    float u = len * 0.2f;
    float fc = 0.0f;
    if (u < 1.0f) {
        float u2 = u * u, u4 = u2 * u2, u5 = u4 * u, u6 = u5 * u, u7 = u6 * u;
        fc = 1.0f - 21.0f * u5 + 35.0f * u6 - 15.0f * u7;
    }
    float pref = 0.6324555320336759f * inv * fc;
    const float PIO5 = 0.6283185307179586f;
#pragma unroll
    for (int n = 1; n <= 8; ++n)
        ef[i * 8 + n - 1] = pref * sinf((float)n * PIO5 * len);
}

// ---------------------------------------------------------------------------
// Fused output-layer GEMM + segment gather (owner-computes, no atomics).
// One block = NPB consecutive nodes. Thread t owns one W_out column (64 regs).
// MG 1: layer1  ->  A_s[c]+= w*hu[s][c] (t<128) ; A_v[d][c]+= w*hu[s][c]*Yv[d]
// MG 2: layer2 s -> A2_s[c] += w_a*hs[s][c] + w_b*(hv[s][:,c].Yv)/sqrt3
// MG 3: layer2 v -> A2_v[d][c] += w_c*hs[s][c]*Yv[d] + w_d*hv[s][d][c]
// ---------------------------------------------------------------------------
template <int MG>
__global__ __launch_bounds__(256) void k_gather(
    const int* __restrict__ rowptr, const int* __restrict__ psnd,
    const float* __restrict__ Yv, const float* __restrict__ hb, int e0, int e1,
    const float* __restrict__ W, int wld, int coloff,
    const float* __restrict__ gS, const float* __restrict__ gV,
    float* __restrict__ outS, float* __restrict__ outV)
{
    constexpr int NPB = 8;
    __shared__ float red[256 * 3];
    const int t = threadIdx.x;
    const int c = t & 127;
    const int hi = t >> 7;
    const int n0 = blockIdx.x * NPB;

    const int wcol = coloff + ((MG == 1) ? t : hi * 128 + c);
    float wreg[64];
#pragma unroll
    for (int k = 0; k < 64; ++k) wreg[k] = W[k * wld + wcol];

    for (int n = n0; n < n0 + NPB; ++n) {
        int rs = rowptr[n], re = rowptr[n + 1];
        if (rs < e0) rs = e0;
        if (re > e1) re = e1;
        float accs = 0.0f, a0 = 0.0f, a1 = 0.0f, a2 = 0.0f;
        for (int i = rs; i < re; ++i) {
            const float* hp = hb + (size_t)(i - e0) * 64;
            float w = 0.0f;
#pragma unroll
            for (int k = 0; k < 64; ++k) w = fmaf(hp[k], wreg[k], w);
            const int s = psnd[i];
            if constexpr (MG == 1) {
                float hv_ = gS[s * 128 + c];
                if (hi == 0) {
                    accs = fmaf(w, hv_, accs);
                } else {
                    float tv = w * hv_;
                    float y0 = Yv[i * 3], y1 = Yv[i * 3 + 1], y2 = Yv[i * 3 + 2];
                    a0 = fmaf(tv, y0, a0); a1 = fmaf(tv, y1, a1); a2 = fmaf(tv, y2, a2);
                }
            } else if constexpr (MG == 2) {
                if (hi == 0) {
                    accs = fmaf(w, gS[s * 128 + c], accs);
                } else {
                    float y0 = Yv[i * 3], y1 = Yv[i * 3 + 1], y2 = Yv[i * 3 + 2];
                    float hd = gV[s * 384 + c] * y0 + gV[s * 384 + 128 + c] * y1
                             + gV[s * 384 + 256 + c] * y2;
                    accs = fmaf(w, hd * 0.57735026919f, accs);
                }
            } else {
                if (hi == 0) {
                    float tv = w * gS[s * 128 + c];
                    float y0 = Yv[i * 3], y1 = Yv[i * 3 + 1], y2 = Yv[i * 3 + 2];
                    a0 = fmaf(tv, y0, a0); a1 = fmaf(tv, y1, a1); a2 = fmaf(tv, y2, a2);
                } else {
                    a0 = fmaf(w, gV[s * 384 + c], a0);
                    a1 = fmaf(w, gV[s * 384 + 128 + c], a1);
                    a2 = fmaf(w, gV[s * 384 + 256 + c], a2);
                }
            }
        }
        // epilogue (no atomics: this block exclusively owns node n)
        if constexpr (MG == 1) {
            if (hi == 0) {
                outS[n * 128 + c] += accs;
            } else {
                outV[n * 384 + c]       += a0;
                outV[n * 384 + 128 + c] += a1;
                outV[n * 384 + 256 + c] += a2;
            }
        } else if constexpr (MG == 2) {
            red[t] = accs;
            __syncthreads();
            if (hi == 0) outS[n * 128 + c] += red[c] + red[128 + c];
            __syncthreads();
        } else {
            red[t * 3] = a0; red[t * 3 + 1] = a1; red[t * 3 + 2] = a2;
            __syncthreads();
            if (hi == 0) {
                outV[n * 384 + c]       += a0 + red[(128 + c) * 3];
                outV[n * 384 + 128 + c] += a1 + red[(128 + c) * 3 + 1];
                outV[n * 384 + 256 + c] += a2 + red[(128 + c) * 3 + 2];
            }
            __syncthreads();
        }
    }
}

// ---------------------------------------------------------------------------
__global__ void k_species(const float* __restrict__ attrs, int* __restrict__ species)
{
    int n = blockIdx.x * 256 + threadIdx.x;
    if (n >= NN) return;
    int sp = 0;
#pragma unroll
    for (int j = 0; j < NEL; ++j)
        if (attrs[n * NEL + j] > 0.5f) sp = j;
    species[n] = sp;
}

__global__ void k_embed(const float* __restrict__ W_emb, const int* __restrict__ species,
                        float* __restrict__ h)
{
    int t = blockIdx.x * 256 + threadIdx.x;
    if (t >= NN * CC) return;
    int n = t >> 7, c = t & 127;
    h[t] = W_emb[species[n] * CC + c];
}

__global__ void k_rmix(const float* __restrict__ Rmid, const float* __restrict__ Rout,
                       float* __restrict__ rmix)
{
    int c = threadIdx.x;
    float s = 0.f;
#pragma unroll
    for (int k = 0; k < 16; ++k) s = fmaf(Rmid[c * 16 + k], Rout[k], s);
    rmix[c] = s;
}

__global__ void k_B1(const int* __restrict__ species,
                     const float* __restrict__ As_l, const float* __restrict__ Av_l,
                     const float* __restrict__ P_s1, const float* __restrict__ P_ss,
                     const float* __restrict__ P_vv, const float* __restrict__ P_v1,
                     const float* __restrict__ P_sv,
                     float* __restrict__ Bs, float* __restrict__ Bv)
{
    int t = blockIdx.x * 256 + threadIdx.x;
    if (t >= NN * CC) return;
    int n = t >> 7, c = t & 127;
    int sp = species[n];
    int pb = sp * CC + c;
    int vb = n * 384 + c;
    float as = As_l[t];
    float a0 = Av_l[vb], a1 = Av_l[vb + CC], a2 = Av_l[vb + 2 * CC];
    Bs[t] = P_s1[pb] * as + P_ss[pb] * as * as
          + P_vv[pb] * (a0 * a0 + a1 * a1 + a2 * a2) * 0.57735026919f;
    float tv = P_v1[pb] + P_sv[pb] * as;
    Bv[vb] = tv * a0; Bv[vb + CC] = tv * a1; Bv[vb + 2 * CC] = tv * a2;
}

__global__ void k_B2(const int* __restrict__ species,
                     const float* __restrict__ As_l, const float* __restrict__ Av_l,
                     const float* __restrict__ P_v1, const float* __restrict__ P_sv,
                     float* __restrict__ Bv)
{
    int t = blockIdx.x * 256 + threadIdx.x;
    if (t >= NN * CC) return;
    int n = t >> 7, c = t & 127;
    int sp = species[n];
    int pb = sp * CC + c;
    int vb = n * 384 + c;
    float as = As_l[t];
    float tv = P_v1[pb] + P_sv[pb] * as;
    Bv[vb] = tv * Av_l[vb];
    Bv[vb + CC] = tv * Av_l[vb + CC];
    Bv[vb + 2 * CC] = tv * Av_l[vb + 2 * CC];
}

__global__ void k_dip1(const float* __restrict__ h_v, const float* __restrict__ R1,
                       float* __restrict__ dip1)
{
    int n = blockIdx.x, l = threadIdx.x;
    const float* hb = h_v + n * 384;
#pragma unroll
    for (int d = 0; d < 3; ++d) {
        float v = hb[d * CC + l] * R1[l] + hb[d * CC + 64 + l] * R1[64 + l];
        for (int o = 32; o > 0; o >>= 1) v += __shfl_down(v, o);
        if (l == 0) dip1[n * 3 + d] = v;
    }
}

__global__ void k_sc(const int* __restrict__ species, const float* __restrict__ h_v,
                     const float* __restrict__ Wsk, float* __restrict__ h2v)
{
    int n = blockIdx.x, f = threadIdx.x;
    int sp = species[n];
    const float* Wp = Wsk + sp * (CC * CC);
    const float* hvn = h_v + n * 384;
    float a0 = 0.f, a1 = 0.f, a2 = 0.f;
    for (int c = 0; c < CC; ++c) {
        float w = Wp[c * CC + f];
        a0 = fmaf(hvn[c], w, a0);
        a1 = fmaf(hvn[CC + c], w, a1);
        a2 = fmaf(hvn[2 * CC + c], w, a2);
    }
    h2v[n * 384 + f] = a0;
    h2v[n * 384 + CC + f] = a1;
    h2v[n * 384 + 2 * CC + f] = a2;
}

__global__ void k_final(const float* __restrict__ h2v, const float* __restrict__ rmix,
                        const float* __restrict__ dip1, const int* __restrict__ batch,
                        const float* __restrict__ charges, const float* __restrict__ pos,
                        float* __restrict__ out)
{
    int n = blockIdx.x, l = threadIdx.x;
    const float* hb = h2v + n * 384;
    float r0 = rmix[l], r1 = rmix[64 + l];
    float red[3];
#pragma unroll
    for (int d = 0; d < 3; ++d) {
        float v = hb[d * CC + l] * r0 + hb[d * CC + 64 + l] * r1;
        for (int o = 32; o > 0; o >>= 1) v += __shfl_down(v, o);
        red[d] = v;
    }
    if (l == 0) {
        int g = batch[n];
        float q = charges[n];
#pragma unroll
        for (int d = 0; d < 3; ++d) {
            float a = dip1[n * 3 + d] + 0.5f * red[d];
            out[48 + n * 3 + d] = a;
            atomicAdd(&out[g * 3 + d], a + q * pos[n * 3 + d]);
        }
    }
}

// ---------------------------------------------------------------------------
extern "C" void kernel_launch(void* const* d_in, const int* in_sizes, int n_in,
                              void* d_out, int out_size, void* d_ws, size_t ws_size,
                              hipStream_t stream)
{
    const float* positions = (const float*)d_in[0];
    const float* node_attrs = (const float*)d_in[1];
    const float* charges = (const float*)d_in[2];
    const float* shifts = (const float*)d_in[3];
    const int*   eidx = (const int*)d_in[4];
    const int*   batch = (const int*)d_in[5];
    const float* W_emb  = (const float*)d_in[7];
    const float* W_up1  = (const float*)d_in[8];
    const float* Wr1_1  = (const float*)d_in[9];
    const float* Wr1_2  = (const float*)d_in[10];
    const float* Wr1_3  = (const float*)d_in[11];
    const float* Wr1_o  = (const float*)d_in[12];
    const float* Wlin1_s = (const float*)d_in[13];
    const float* Wlin1_v = (const float*)d_in[14];
    const float* P1_s1 = (const float*)d_in[15];
    const float* P1_ss = (const float*)d_in[16];
    const float* P1_vv = (const float*)d_in[17];
    const float* P1_v1 = (const float*)d_in[18];
    const float* P1_sv = (const float*)d_in[19];
    const float* Lp1_s = (const float*)d_in[20];
    const float* Lp1_v = (const float*)d_in[21];
    const float* R1    = (const float*)d_in[22];
    const float* Wsk   = (const float*)d_in[23];
    const float* Wup2_s = (const float*)d_in[24];
    const float* Wup2_v = (const float*)d_in[25];
    const float* Wr2_1 = (const float*)d_in[26];
    const float* Wr2_2 = (const float*)d_in[27];
    const float* Wr2_3 = (const float*)d_in[28];
    const float* Wr2_o = (const float*)d_in[29];
    const float* Wlin2_s = (const float*)d_in[30];
    const float* Wlin2_v = (const float*)d_in[31];
    const float* P2_v1 = (const float*)d_in[32];
    const float* P2_sv = (const float*)d_in[33];
    const float* Lp2_v = (const float*)d_in[34];
    const float* Rmid  = (const float*)d_in[35];
    const float* Rout  = (const float*)d_in[36];
    (void)in_sizes; (void)n_in; (void)out_size;

    const int* snd = eidx;
    const int* rcv = eidx + EE;
    float* out = (float*)d_out;

    const int NCH  = (ws_size >= (size_t)175 * 1024 * 1024) ? 1 : 2;
    const int ECHn = EE / NCH;

    char* ws = (char*)d_ws;
    size_t off = 0;
    auto alloc = [&](size_t bytes) -> float* {
        float* p = (float*)(ws + off);
        off = (off + bytes + 255) & ~(size_t)255;
        return p;
    };
    int*   species = (int*)alloc((size_t)NN * 4);
    int*   deg     = (int*)alloc((size_t)NN * 4);
    int*   rowptr  = (int*)alloc((size_t)(NN + 16) * 4);
    int*   cursor  = (int*)alloc((size_t)NN * 4);
    int*   perm    = (int*)alloc((size_t)EE * 4);
    int*   psnd    = (int*)alloc((size_t)EE * 4);
    float* Yv   = alloc((size_t)EE * 3 * 4);
    float* ef   = alloc((size_t)EE * 8 * 4);
    float* A_s  = alloc((size_t)NN * CC * 4);       // A_s / As_l (in place); A2_s
    float* A_v  = alloc((size_t)NN * 3 * CC * 4);   // A_v / Av_l / Bv / A2_v / B2v
    float* hbuf = alloc((size_t)NN * CC * 4);       // h -> Bs -> hs
    float* hu   = alloc((size_t)NN * CC * 4);       // hu -> h_s
    float* h_v  = alloc((size_t)NN * 3 * CC * 4);   // layer-1 vector feats (kept for sc_v)
    float* hv   = alloc((size_t)NN * 3 * CC * 4);
    float* h2v  = alloc((size_t)NN * 3 * CC * 4);
    float* dip1 = alloc((size_t)NN * 3 * 4);
    float* rmix = alloc((size_t)CC * 4);
    float* hbA  = alloc((size_t)ECHn * 64 * 4);
    float* hbB  = alloc((size_t)ECHn * 64 * 4);

    const float inv16 = 1.0f / 16.0f;
    const float one = 1.0f;

    hipMemsetAsync(d_out, 0, 48 * 4, stream);
    hipMemsetAsync(deg, 0, (size_t)NN * 4, stream);
    hipMemsetAsync(A_s, 0, (size_t)NN * CC * 4, stream);
    hipMemsetAsync(A_v, 0, (size_t)NN * 3 * CC * 4, stream);

    // ---- CSR build + permuted geometry ----
    k_count<<<cdiv(EE, 256), 256, 0, stream>>>(rcv, deg);
    k_scan<<<1, 256, 0, stream>>>(deg, rowptr, cursor);
    k_fill<<<cdiv(EE, 256), 256, 0, stream>>>(rcv, cursor, perm);
    k_sortseg<<<cdiv(NN, 256), 256, 0, stream>>>(rowptr, perm);
    k_geom_perm<<<cdiv(EE, 256), 256, 0, stream>>>(positions, shifts, snd, rcv, perm, Yv, ef, psnd);

    k_species<<<cdiv(NN, 256), 256, 0, stream>>>(node_attrs, species);
    k_embed<<<cdiv(NN * CC, 256), 256, 0, stream>>>(W_emb, species, hbuf);
    k_rmix<<<1, CC, 0, stream>>>(Rmid, Rout, rmix);

    // hu = h @ W_up1
    rowgemm_k<128, 128, 0><<<cdiv(NN, 64), 256, 0, stream>>>(
        hbuf, 128, W_up1, 128, hu, 128, NN, one);

    // ---- layer 1: edge MLP + fused gather ----
    for (int ch = 0; ch < NCH; ++ch) {
        int e0 = ch * ECHn, e1 = e0 + ECHn;
        rowgemm_k<8, 64, 1><<<cdiv(ECHn, 128), 256, 0, stream>>>(
            ef + (size_t)e0 * 8, 8, Wr1_1, 64, hbA, 64, ECHn, one);
        rowgemm_k<64, 64, 1><<<cdiv(ECHn, 128), 256, 0, stream>>>(
            hbA, 64, Wr1_2, 64, hbB, 64, ECHn, one);
        rowgemm_k<64, 64, 1><<<cdiv(ECHn, 128), 256, 0, stream>>>(
            hbB, 64, Wr1_3, 64, hbA, 64, ECHn, one);
        k_gather<1><<<NN / 8, 256, 0, stream>>>(
            rowptr, psnd, Yv, hbA, e0, e1, Wr1_o, 256, 0, hu, nullptr, A_s, A_v);
    }

    // ---- layer 1 node side (Wlin in place) ----
    rowgemm_k<128, 128, 0><<<cdiv(NN, 64), 256, 0, stream>>>(
        A_s, 128, Wlin1_s, 128, A_s, 128, NN, inv16);
    rowgemm_k<128, 128, 0><<<cdiv(3 * NN, 64), 256, 0, stream>>>(
        A_v, 128, Wlin1_v, 128, A_v, 128, 3 * NN, inv16);
    k_B1<<<cdiv(NN * CC, 256), 256, 0, stream>>>(
        species, A_s, A_v, P1_s1, P1_ss, P1_vv, P1_v1, P1_sv, hbuf /*Bs*/, A_v /*Bv*/);
    rowgemm_k<128, 128, 0><<<cdiv(NN, 64), 256, 0, stream>>>(
        hbuf, 128, Lp1_s, 128, hu /*h_s*/, 128, NN, one);
    rowgemm_k<128, 128, 0><<<cdiv(3 * NN, 64), 256, 0, stream>>>(
        A_v /*Bv*/, 128, Lp1_v, 128, h_v, 128, 3 * NN, one);
    k_dip1<<<NN, 64, 0, stream>>>(h_v, R1, dip1);
    rowgemm_k<128, 128, 0><<<cdiv(NN, 64), 256, 0, stream>>>(
        hu /*h_s*/, 128, Wup2_s, 128, hbuf /*hs*/, 128, NN, one);
    rowgemm_k<128, 128, 0><<<cdiv(3 * NN, 64), 256, 0, stream>>>(
        h_v, 128, Wup2_v, 128, hv, 128, 3 * NN, one);

    // ---- layer 2: edge MLP + fused gathers ----
    hipMemsetAsync(A_s, 0, (size_t)NN * CC * 4, stream);
    hipMemsetAsync(A_v, 0, (size_t)NN * 3 * CC * 4, stream);
    for (int ch = 0; ch < NCH; ++ch) {
        int e0 = ch * ECHn, e1 = e0 + ECHn;
        rowgemm_k<8, 64, 1><<<cdiv(ECHn, 128), 256, 0, stream>>>(
            ef + (size_t)e0 * 8, 8, Wr2_1, 64, hbA, 64, ECHn, one);
        rowgemm_k<64, 64, 1><<<cdiv(ECHn, 128), 256, 0, stream>>>(
            hbA, 64, Wr2_2, 64, hbB, 64, ECHn, one);
        rowgemm_k<64, 64, 1><<<cdiv(ECHn, 128), 256, 0, stream>>>(
            hbB, 64, Wr2_3, 64, hbA, 64, ECHn, one);
        k_gather<2><<<NN / 8, 256, 0, stream>>>(
            rowptr, psnd, Yv, hbA, e0, e1, Wr2_o, 512, 0, hbuf /*hs*/, hv, A_s, nullptr);
        k_gather<3><<<NN / 8, 256, 0, stream>>>(
            rowptr, psnd, Yv, hbA, e0, e1, Wr2_o, 512, 256, hbuf /*hs*/, hv, nullptr, A_v);
    }

    // ---- layer 2 node side ----
    rowgemm_k<128, 128, 0><<<cdiv(NN, 64), 256, 0, stream>>>(
        A_s, 128, Wlin2_s, 128, A_s, 128, NN, inv16);
    rowgemm_k<128, 128, 0><<<cdiv(3 * NN, 64), 256, 0, stream>>>(
        A_v, 128, Wlin2_v, 128, A_v, 128, 3 * NN, inv16);
    k_sc<<<NN, 128, 0, stream>>>(species, h_v, Wsk, h2v);
    k_B2<<<cdiv(NN * CC, 256), 256, 0, stream>>>(species, A_s, A_v, P2_v1, P2_sv, A_v /*B2v*/);
    rowgemm_k<128, 128, 6><<<cdiv(3 * NN, 64), 256, 0, stream>>>(
        A_v /*B2v*/, 128, Lp2_v, 128, h2v, 128, 3 * NN, one);

    k_final<<<NN, 64, 0, stream>>>(h2v, rmix, dip1, batch, charges, positions, out);
}

// Round 3
// 1235.446 us; speedup vs baseline: 6.1585x; 1.1888x over previous
//
#include <hip/hip_runtime.h>

#define NN 10000
#define EE 160000
#define CC 128
#define NEL 10
#define NGR 16

static inline int cdiv(int a, int b) { return (a + b - 1) / b; }

__device__ __forceinline__ float silu_f(float x) { return x / (1.0f + __expf(-x)); }

// ---------------------------------------------------------------------------
// Generic row-GEMM: out[r][c] = sum_k in[r][k] * W[k][c]   (W row-major, w_ld)
// MODE 0: store   1: store+silu   6: out += (accumulate)
// Safe for in-place (out==in) since all global reads complete before stores.
// ---------------------------------------------------------------------------
template <int K, int N, int MODE>
__global__ __launch_bounds__(256) void rowgemm_k(
    const float* __restrict__ in, int in_ld,
    const float* __restrict__ W, int w_ld,
    float* __restrict__ out, int out_ld,
    int R, float scale)
{
    constexpr int TR = 8192 / N;     // rows per tile (64 for N=128, 128 for N=64)
    constexpr int CG = N / 8;        // col groups of 8
    constexpr int RG = 256 / CG;
    static_assert(RG * 4 == TR, "tile shape mismatch");
    constexpr int KC = (K < 64 ? K : 64);

    __shared__ float Wl[KC][N];
    __shared__ float inT[K][TR + 4];

    const int tid = threadIdx.x;
    const int cg = tid % CG, rg = tid / CG;
    const int c0 = cg * 8, r0 = rg * 4;
    const int row0 = blockIdx.x * TR;

    for (int i = tid; i < K * TR; i += 256) {
        int r = i / K, k = i - r * K;
        int row = row0 + r;
        inT[k][r] = (row < R) ? in[row * in_ld + k] : 0.0f;
    }

    float acc[4][8];
#pragma unroll
    for (int i = 0; i < 4; ++i)
#pragma unroll
        for (int j = 0; j < 8; ++j) acc[i][j] = 0.0f;

    for (int kc = 0; kc < K; kc += KC) {
        __syncthreads();
        for (int i = tid; i < KC * N; i += 256) {
            int k = i / N, c = i - k * N;
            Wl[k][c] = W[(kc + k) * w_ld + c];
        }
        __syncthreads();
#pragma unroll 8
        for (int kk = 0; kk < KC; ++kk) {
            const float4 a  = *(const float4*)&inT[kc + kk][r0];
            const float4 b0 = *(const float4*)&Wl[kk][c0];
            const float4 b1 = *(const float4*)&Wl[kk][c0 + 4];
            const float av[4] = {a.x, a.y, a.z, a.w};
            const float bv[8] = {b0.x, b0.y, b0.z, b0.w, b1.x, b1.y, b1.z, b1.w};
#pragma unroll
            for (int i = 0; i < 4; ++i)
#pragma unroll
                for (int j = 0; j < 8; ++j)
                    acc[i][j] = fmaf(av[i], bv[j], acc[i][j]);
        }
    }

#pragma unroll
    for (int i = 0; i < 4; ++i) {
        int row = row0 + r0 + i;
        if (row >= R) break;
#pragma unroll
        for (int j = 0; j < 8; ++j) {
            float v = acc[i][j] * scale;
            if constexpr (MODE == 1) v = silu_f(v);
            int idx = row * out_ld + c0 + j;
            if constexpr (MODE == 6) out[idx] += v;
            else out[idx] = v;
        }
    }
}

// ---------------------------------------------------------------------------
// CSR build
// ---------------------------------------------------------------------------
__global__ void k_count(const int* __restrict__ rcv, int* __restrict__ deg)
{
    int e = blockIdx.x * 256 + threadIdx.x;
    if (e < EE) atomicAdd(&deg[rcv[e]], 1);
}

__global__ __launch_bounds__(256) void k_scan(const int* __restrict__ deg,
                                              int* __restrict__ rowptr,
                                              int* __restrict__ cursor)
{
    __shared__ int part[256];
    const int t = threadIdx.x;
    const int PER = (NN + 255) / 256;   // 40
    int base = t * PER;
    int s = 0;
    for (int j = 0; j < PER; ++j) { int idx = base + j; if (idx < NN) s += deg[idx]; }
    part[t] = s;
    __syncthreads();
    for (int off = 1; off < 256; off <<= 1) {
        int v = (t >= off) ? part[t - off] : 0;
        __syncthreads();
        part[t] += v;
        __syncthreads();
    }
    int run = (t == 0) ? 0 : part[t - 1];
    for (int j = 0; j < PER; ++j) {
        int idx = base + j;
        if (idx < NN) { rowptr[idx] = run; cursor[idx] = run; run += deg[idx]; }
    }
    if (t == 255) rowptr[NN] = part[255];
}

__global__ void k_fill(const int* __restrict__ rcv, int* __restrict__ cursor,
                       int* __restrict__ perm)
{
    int e = blockIdx.x * 256 + threadIdx.x;
    if (e >= EE) return;
    int pos = atomicAdd(&cursor[rcv[e]], 1);
    perm[pos] = e;
}

__global__ void k_sortseg(const int* __restrict__ rowptr, int* __restrict__ perm)
{
    int n = blockIdx.x * 256 + threadIdx.x;
    if (n >= NN) return;
    int a = rowptr[n], b = rowptr[n + 1];
    for (int i = a + 1; i < b; ++i) {
        int v = perm[i];
        int j = i - 1;
        while (j >= a && perm[j] > v) { perm[j + 1] = perm[j]; --j; }
        perm[j + 1] = v;
    }
}

// geometry, written in CSR (permuted) edge order
__global__ void k_geom_perm(const float* __restrict__ pos, const float* __restrict__ shifts,
                            const int* __restrict__ snd, const int* __restrict__ rcv,
                            const int* __restrict__ perm,
                            float* __restrict__ Yv, float* __restrict__ ef,
                            int* __restrict__ psnd)
{
    int i = blockIdx.x * 256 + threadIdx.x;
    if (i >= EE) return;
    int e = perm[i];
    int s = snd[e], r = rcv[e];
    psnd[i] = s;
    float vx = pos[r * 3 + 0] - pos[s * 3 + 0] + shifts[e * 3 + 0];
    float vy = pos[r * 3 + 1] - pos[s * 3 + 1] + shifts[e * 3 + 1];
    float vz = pos[r * 3 + 2] - pos[s * 3 + 2] + shifts[e * 3 + 2];
    float len = sqrtf(vx * vx + vy * vy + vz * vz + 1e-12f);
    float inv = 1.0f / len;
    const float SQ3 = 1.7320508075688772f;
    Yv[i * 3 + 0] = SQ3 * vx * inv;
    Yv[i * 3 + 1] = SQ3 * vy * inv;
    Yv[i * 3 + 2] = SQ3 * vz * inv;
    float u = len * 0.2f;
    float fc = 0.0f;
    if (u < 1.0f) {
        float u2 = u * u, u4 = u2 * u2, u5 = u4 * u, u6 = u5 * u, u7 = u6 * u;
        fc = 1.0f - 21.0f * u5 + 35.0f * u6 - 15.0f * u7;
    }
    float pref = 0.6324555320336759f * inv * fc;
    const float PIO5 = 0.6283185307179586f;
#pragma unroll
    for (int n = 1; n <= 8; ++n)
        ef[i * 8 + n - 1] = pref * sinf((float)n * PIO5 * len);
}

// ---------------------------------------------------------------------------
// Fused output-layer GEMM + segment gather (owner-computes, no atomics).
// One block = NPB consecutive nodes. Thread t owns one W_out column (64 regs).
// MG 1: layer1  ->  A_s[c]+= w*hu[s][c] (t<128) ; A_v[d][c]+= w*hu[s][c]*Yv[d]
// MG 2: layer2 s -> A2_s[c] += w_a*hs[s][c] + w_b*(hv[s][:,c].Yv)/sqrt3
// MG 3: layer2 v -> A2_v[d][c] += w_c*hs[s][c]*Yv[d] + w_d*hv[s][d][c]
// ---------------------------------------------------------------------------
template <int MG>
__global__ __launch_bounds__(256) void k_gather(
    const int* __restrict__ rowptr, const int* __restrict__ psnd,
    const float* __restrict__ Yv, const float* __restrict__ hb, int e0, int e1,
    const float* __restrict__ W, int wld, int coloff,
    const float* __restrict__ gS, const float* __restrict__ gV,
    float* __restrict__ outS, float* __restrict__ outV)
{
    constexpr int NPB = 8;
    __shared__ float red[256 * 3];
    const int t = threadIdx.x;
    const int c = t & 127;
    const int hi = t >> 7;
    const int n0 = blockIdx.x * NPB;

    const int wcol = coloff + ((MG == 1) ? t : hi * 128 + c);
    float wreg[64];
#pragma unroll
    for (int k = 0; k < 64; ++k) wreg[k] = W[k * wld + wcol];

    for (int n = n0; n < n0 + NPB; ++n) {
        int rs = rowptr[n], re = rowptr[n + 1];
        if (rs < e0) rs = e0;
        if (re > e1) re = e1;
        float accs = 0.0f, a0 = 0.0f, a1 = 0.0f, a2 = 0.0f;
        for (int i = rs; i < re; ++i) {
            const float* hp = hb + (size_t)(i - e0) * 64;
            float w = 0.0f;
#pragma unroll
            for (int k = 0; k < 64; ++k) w = fmaf(hp[k], wreg[k], w);
            const int s = psnd[i];
            if constexpr (MG == 1) {
                float hv_ = gS[s * 128 + c];
                if (hi == 0) {
                    accs = fmaf(w, hv_, accs);
                } else {
                    float tv = w * hv_;
                    float y0 = Yv[i * 3], y1 = Yv[i * 3 + 1], y2 = Yv[i * 3 + 2];
                    a0 = fmaf(tv, y0, a0); a1 = fmaf(tv, y1, a1); a2 = fmaf(tv, y2, a2);
                }
            } else if constexpr (MG == 2) {
                if (hi == 0) {
                    accs = fmaf(w, gS[s * 128 + c], accs);
                } else {
                    float y0 = Yv[i * 3], y1 = Yv[i * 3 + 1], y2 = Yv[i * 3 + 2];
                    float hd = gV[s * 384 + c] * y0 + gV[s * 384 + 128 + c] * y1
                             + gV[s * 384 + 256 + c] * y2;
                    accs = fmaf(w, hd * 0.57735026919f, accs);
                }
            } else {
                if (hi == 0) {
                    float tv = w * gS[s * 128 + c];
                    float y0 = Yv[i * 3], y1 = Yv[i * 3 + 1], y2 = Yv[i * 3 + 2];
                    a0 = fmaf(tv, y0, a0); a1 = fmaf(tv, y1, a1); a2 = fmaf(tv, y2, a2);
                } else {
                    a0 = fmaf(w, gV[s * 384 + c], a0);
                    a1 = fmaf(w, gV[s * 384 + 128 + c], a1);
                    a2 = fmaf(w, gV[s * 384 + 256 + c], a2);
                }
            }
        }
        // epilogue (no atomics: this block exclusively owns node n)
        if constexpr (MG == 1) {
            if (hi == 0) {
                outS[n * 128 + c] += accs;
            } else {
                outV[n * 384 + c]       += a0;
                outV[n * 384 + 128 + c] += a1;
                outV[n * 384 + 256 + c] += a2;
            }
        } else if constexpr (MG == 2) {
            red[t] = accs;
            __syncthreads();
            if (hi == 0) outS[n * 128 + c] += red[c] + red[128 + c];
            __syncthreads();
        } else {
            red[t * 3] = a0; red[t * 3 + 1] = a1; red[t * 3 + 2] = a2;
            __syncthreads();
            if (hi == 0) {
                outV[n * 384 + c]       += a0 + red[(128 + c) * 3];
                outV[n * 384 + 128 + c] += a1 + red[(128 + c) * 3 + 1];
                outV[n * 384 + 256 + c] += a2 + red[(128 + c) * 3 + 2];
            }
            __syncthreads();
        }
    }
}

// ---------------------------------------------------------------------------
__global__ void k_species(const float* __restrict__ attrs, int* __restrict__ species)
{
    int n = blockIdx.x * 256 + threadIdx.x;
    if (n >= NN) return;
    int sp = 0;
#pragma unroll
    for (int j = 0; j < NEL; ++j)
        if (attrs[n * NEL + j] > 0.5f) sp = j;
    species[n] = sp;
}

__global__ void k_embed(const float* __restrict__ W_emb, const int* __restrict__ species,
                        float* __restrict__ h)
{
    int t = blockIdx.x * 256 + threadIdx.x;
    if (t >= NN * CC) return;
    int n = t >> 7, c = t & 127;
    h[t] = W_emb[species[n] * CC + c];
}

__global__ void k_rmix(const float* __restrict__ Rmid, const float* __restrict__ Rout,
                       float* __restrict__ rmix)
{
    int c = threadIdx.x;
    float s = 0.f;
#pragma unroll
    for (int k = 0; k < 16; ++k) s = fmaf(Rmid[c * 16 + k], Rout[k], s);
    rmix[c] = s;
}

__global__ void k_B1(const int* __restrict__ species,
                     const float* __restrict__ As_l, const float* __restrict__ Av_l,
                     const float* __restrict__ P_s1, const float* __restrict__ P_ss,
                     const float* __restrict__ P_vv, const float* __restrict__ P_v1,
                     const float* __restrict__ P_sv,
                     float* __restrict__ Bs, float* __restrict__ Bv)
{
    int t = blockIdx.x * 256 + threadIdx.x;
    if (t >= NN * CC) return;
    int n = t >> 7, c = t & 127;
    int sp = species[n];
    int pb = sp * CC + c;
    int vb = n * 384 + c;
    float as = As_l[t];
    float a0 = Av_l[vb], a1 = Av_l[vb + CC], a2 = Av_l[vb + 2 * CC];
    Bs[t] = P_s1[pb] * as + P_ss[pb] * as * as
          + P_vv[pb] * (a0 * a0 + a1 * a1 + a2 * a2) * 0.57735026919f;
    float tv = P_v1[pb] + P_sv[pb] * as;
    Bv[vb] = tv * a0; Bv[vb + CC] = tv * a1; Bv[vb + 2 * CC] = tv * a2;
}

__global__ void k_B2(const int* __restrict__ species,
                     const float* __restrict__ As_l, const float* __restrict__ Av_l,
                     const float* __restrict__ P_v1, const float* __restrict__ P_sv,
                     float* __restrict__ Bv)
{
    int t = blockIdx.x * 256 + threadIdx.x;
    if (t >= NN * CC) return;
    int n = t >> 7, c = t & 127;
    int sp = species[n];
    int pb = sp * CC + c;
    int vb = n * 384 + c;
    float as = As_l[t];
    float tv = P_v1[pb] + P_sv[pb] * as;
    Bv[vb] = tv * Av_l[vb];
    Bv[vb + CC] = tv * Av_l[vb + CC];
    Bv[vb + 2 * CC] = tv * Av_l[vb + 2 * CC];
}

__global__ void k_dip1(const float* __restrict__ h_v, const float* __restrict__ R1,
                       float* __restrict__ dip1)
{
    int n = blockIdx.x, l = threadIdx.x;
    const float* hb = h_v + n * 384;
#pragma unroll
    for (int d = 0; d < 3; ++d) {
        float v = hb[d * CC + l] * R1[l] + hb[d * CC + 64 + l] * R1[64 + l];
        for (int o = 32; o > 0; o >>= 1) v += __shfl_down(v, o);
        if (l == 0) dip1[n * 3 + d] = v;
    }
}

__global__ void k_sc(const int* __restrict__ species, const float* __restrict__ h_v,
                     const float* __restrict__ Wsk, float* __restrict__ h2v)
{
    int n = blockIdx.x, f = threadIdx.x;
    int sp = species[n];
    const float* Wp = Wsk + sp * (CC * CC);
    const float* hvn = h_v + n * 384;
    float a0 = 0.f, a1 = 0.f, a2 = 0.f;
    for (int c = 0; c < CC; ++c) {
        float w = Wp[c * CC + f];
        a0 = fmaf(hvn[c], w, a0);
        a1 = fmaf(hvn[CC + c], w, a1);
        a2 = fmaf(hvn[2 * CC + c], w, a2);
    }
    h2v[n * 384 + f] = a0;
    h2v[n * 384 + CC + f] = a1;
    h2v[n * 384 + 2 * CC + f] = a2;
}

// per-node output: atomic dipole -> out[48+...], graph contribution -> tot[n][3]
__global__ void k_node_out(const float* __restrict__ h2v, const float* __restrict__ rmix,
                           const float* __restrict__ dip1,
                           const float* __restrict__ charges, const float* __restrict__ pos,
                           float* __restrict__ out, float* __restrict__ tot)
{
    int n = blockIdx.x, l = threadIdx.x;
    const float* hb = h2v + n * 384;
    float r0 = rmix[l], r1 = rmix[64 + l];
    float red[3];
#pragma unroll
    for (int d = 0; d < 3; ++d) {
        float v = hb[d * CC + l] * r0 + hb[d * CC + 64 + l] * r1;
        for (int o = 32; o > 0; o >>= 1) v += __shfl_down(v, o);
        red[d] = v;
    }
    if (l == 0) {
        float q = charges[n];
#pragma unroll
        for (int d = 0; d < 3; ++d) {
            float a = dip1[n * 3 + d] + 0.5f * red[d];
            out[48 + n * 3 + d] = a;
            tot[n * 3 + d] = a + q * pos[n * 3 + d];
        }
    }
}

// graph totals: one block per graph, no atomics
__global__ __launch_bounds__(256) void k_greduce(const float* __restrict__ tot,
                                                 const int* __restrict__ batch,
                                                 float* __restrict__ out)
{
    __shared__ float r[256 * 3];
    const int g = blockIdx.x;
    const int t = threadIdx.x;
    float s0 = 0.f, s1 = 0.f, s2 = 0.f;
    for (int n = t; n < NN; n += 256) {
        if (batch[n] == g) {
            s0 += tot[n * 3]; s1 += tot[n * 3 + 1]; s2 += tot[n * 3 + 2];
        }
    }
    r[t] = s0; r[256 + t] = s1; r[512 + t] = s2;
    __syncthreads();
    for (int off = 128; off > 0; off >>= 1) {
        if (t < off) {
            r[t] += r[t + off];
            r[256 + t] += r[256 + t + off];
            r[512 + t] += r[512 + t + off];
        }
        __syncthreads();
    }
    if (t < 3) out[g * 3 + t] = r[t * 256];
}

// ---------------------------------------------------------------------------
extern "C" void kernel_launch(void* const* d_in, const int* in_sizes, int n_in,
                              void* d_out, int out_size, void* d_ws, size_t ws_size,
                              hipStream_t stream)
{
    const float* positions = (const float*)d_in[0];
    const float* node_attrs = (const float*)d_in[1];
    const float* charges = (const float*)d_in[2];
    const float* shifts = (const float*)d_in[3];
    const int*   eidx = (const int*)d_in[4];
    const int*   batch = (const int*)d_in[5];
    const float* W_emb  = (const float*)d_in[7];
    const float* W_up1  = (const float*)d_in[8];
    const float* Wr1_1  = (const float*)d_in[9];
    const float* Wr1_2  = (const float*)d_in[10];
    const float* Wr1_3  = (const float*)d_in[11];
    const float* Wr1_o  = (const float*)d_in[12];
    const float* Wlin1_s = (const float*)d_in[13];
    const float* Wlin1_v = (const float*)d_in[14];
    const float* P1_s1 = (const float*)d_in[15];
    const float* P1_ss = (const float*)d_in[16];
    const float* P1_vv = (const float*)d_in[17];
    const float* P1_v1 = (const float*)d_in[18];
    const float* P1_sv = (const float*)d_in[19];
    const float* Lp1_s = (const float*)d_in[20];
    const float* Lp1_v = (const float*)d_in[21];
    const float* R1    = (const float*)d_in[22];
    const float* Wsk   = (const float*)d_in[23];
    const float* Wup2_s = (const float*)d_in[24];
    const float* Wup2_v = (const float*)d_in[25];
    const float* Wr2_1 = (const float*)d_in[26];
    const float* Wr2_2 = (const float*)d_in[27];
    const float* Wr2_3 = (const float*)d_in[28];
    const float* Wr2_o = (const float*)d_in[29];
    const float* Wlin2_s = (const float*)d_in[30];
    const float* Wlin2_v = (const float*)d_in[31];
    const float* P2_v1 = (const float*)d_in[32];
    const float* P2_sv = (const float*)d_in[33];
    const float* Lp2_v = (const float*)d_in[34];
    const float* Rmid  = (const float*)d_in[35];
    const float* Rout  = (const float*)d_in[36];
    (void)in_sizes; (void)n_in; (void)out_size;

    const int* snd = eidx;
    const int* rcv = eidx + EE;
    float* out = (float*)d_out;

    const int NCH  = (ws_size >= (size_t)175 * 1024 * 1024) ? 1 : 2;
    const int ECHn = EE / NCH;

    char* ws = (char*)d_ws;
    size_t off = 0;
    auto alloc = [&](size_t bytes) -> float* {
        float* p = (float*)(ws + off);
        off = (off + bytes + 255) & ~(size_t)255;
        return p;
    };
    int*   species = (int*)alloc((size_t)NN * 4);
    int*   deg     = (int*)alloc((size_t)NN * 4);
    int*   rowptr  = (int*)alloc((size_t)(NN + 16) * 4);
    int*   cursor  = (int*)alloc((size_t)NN * 4);
    int*   perm    = (int*)alloc((size_t)EE * 4);
    int*   psnd    = (int*)alloc((size_t)EE * 4);
    float* Yv   = alloc((size_t)EE * 3 * 4);
    float* ef   = alloc((size_t)EE * 8 * 4);
    float* A_s  = alloc((size_t)NN * CC * 4);       // A_s / As_l (in place); A2_s
    float* A_v  = alloc((size_t)NN * 3 * CC * 4);   // A_v / Av_l / Bv / A2_v / B2v
    float* hbuf = alloc((size_t)NN * CC * 4);       // h -> Bs -> hs
    float* hu   = alloc((size_t)NN * CC * 4);       // hu -> h_s
    float* h_v  = alloc((size_t)NN * 3 * CC * 4);   // layer-1 vector feats (kept for sc_v)
    float* hv   = alloc((size_t)NN * 3 * CC * 4);
    float* h2v  = alloc((size_t)NN * 3 * CC * 4);
    float* dip1 = alloc((size_t)NN * 3 * 4);
    float* rmix = alloc((size_t)CC * 4);
    float* tot  = alloc((size_t)NN * 3 * 4);
    float* hbA  = alloc((size_t)ECHn * 64 * 4);
    float* hbB  = alloc((size_t)ECHn * 64 * 4);

    const float inv16 = 1.0f / 16.0f;
    const float one = 1.0f;

    hipMemsetAsync(deg, 0, (size_t)NN * 4, stream);
    hipMemsetAsync(A_s, 0, (size_t)NN * CC * 4, stream);
    hipMemsetAsync(A_v, 0, (size_t)NN * 3 * CC * 4, stream);

    // ---- CSR build + permuted geometry ----
    k_count<<<cdiv(EE, 256), 256, 0, stream>>>(rcv, deg);
    k_scan<<<1, 256, 0, stream>>>(deg, rowptr, cursor);
    k_fill<<<cdiv(EE, 256), 256, 0, stream>>>(rcv, cursor, perm);
    k_sortseg<<<cdiv(NN, 256), 256, 0, stream>>>(rowptr, perm);
    k_geom_perm<<<cdiv(EE, 256), 256, 0, stream>>>(positions, shifts, snd, rcv, perm, Yv, ef, psnd);

    k_species<<<cdiv(NN, 256), 256, 0, stream>>>(node_attrs, species);
    k_embed<<<cdiv(NN * CC, 256), 256, 0, stream>>>(W_emb, species, hbuf);
    k_rmix<<<1, CC, 0, stream>>>(Rmid, Rout, rmix);

    // hu = h @ W_up1
    rowgemm_k<128, 128, 0><<<cdiv(NN, 64), 256, 0, stream>>>(
        hbuf, 128, W_up1, 128, hu, 128, NN, one);

    // ---- layer 1: edge MLP + fused gather ----
    for (int ch = 0; ch < NCH; ++ch) {
        int e0 = ch * ECHn, e1 = e0 + ECHn;
        rowgemm_k<8, 64, 1><<<cdiv(ECHn, 128), 256, 0, stream>>>(
            ef + (size_t)e0 * 8, 8, Wr1_1, 64, hbA, 64, ECHn, one);
        rowgemm_k<64, 64, 1><<<cdiv(ECHn, 128), 256, 0, stream>>>(
            hbA, 64, Wr1_2, 64, hbB, 64, ECHn, one);
        rowgemm_k<64, 64, 1><<<cdiv(ECHn, 128), 256, 0, stream>>>(
            hbB, 64, Wr1_3, 64, hbA, 64, ECHn, one);
        k_gather<1><<<NN / 8, 256, 0, stream>>>(
            rowptr, psnd, Yv, hbA, e0, e1, Wr1_o, 256, 0, hu, nullptr, A_s, A_v);
    }

    // ---- layer 1 node side (Wlin in place) ----
    rowgemm_k<128, 128, 0><<<cdiv(NN, 64), 256, 0, stream>>>(
        A_s, 128, Wlin1_s, 128, A_s, 128, NN, inv16);
    rowgemm_k<128, 128, 0><<<cdiv(3 * NN, 64), 256, 0, stream>>>(
        A_v, 128, Wlin1_v, 128, A_v, 128, 3 * NN, inv16);
    k_B1<<<cdiv(NN * CC, 256), 256, 0, stream>>>(
        species, A_s, A_v, P1_s1, P1_ss, P1_vv, P1_v1, P1_sv, hbuf /*Bs*/, A_v /*Bv*/);
    rowgemm_k<128, 128, 0><<<cdiv(NN, 64), 256, 0, stream>>>(
        hbuf, 128, Lp1_s, 128, hu /*h_s*/, 128, NN, one);
    rowgemm_k<128, 128, 0><<<cdiv(3 * NN, 64), 256, 0, stream>>>(
        A_v /*Bv*/, 128, Lp1_v, 128, h_v, 128, 3 * NN, one);
    k_dip1<<<NN, 64, 0, stream>>>(h_v, R1, dip1);
    rowgemm_k<128, 128, 0><<<cdiv(NN, 64), 256, 0, stream>>>(
        hu /*h_s*/, 128, Wup2_s, 128, hbuf /*hs*/, 128, NN, one);
    rowgemm_k<128, 128, 0><<<cdiv(3 * NN, 64), 256, 0, stream>>>(
        h_v, 128, Wup2_v, 128, hv, 128, 3 * NN, one);

    // ---- layer 2: edge MLP + fused gathers ----
    hipMemsetAsync(A_s, 0, (size_t)NN * CC * 4, stream);
    hipMemsetAsync(A_v, 0, (size_t)NN * 3 * CC * 4, stream);
    for (int ch = 0; ch < NCH; ++ch) {
        int e0 = ch * ECHn, e1 = e0 + ECHn;
        rowgemm_k<8, 64, 1><<<cdiv(ECHn, 128), 256, 0, stream>>>(
            ef + (size_t)e0 * 8, 8, Wr2_1, 64, hbA, 64, ECHn, one);
        rowgemm_k<64, 64, 1><<<cdiv(ECHn, 128), 256, 0, stream>>>(
            hbA, 64, Wr2_2, 64, hbB, 64, ECHn, one);
        rowgemm_k<64, 64, 1><<<cdiv(ECHn, 128), 256, 0, stream>>>(
            hbB, 64, Wr2_3, 64, hbA, 64, ECHn, one);
        k_gather<2><<<NN / 8, 256, 0, stream>>>(
            rowptr, psnd, Yv, hbA, e0, e1, Wr2_o, 512, 0, hbuf /*hs*/, hv, A_s, nullptr);
        k_gather<3><<<NN / 8, 256, 0, stream>>>(
            rowptr, psnd, Yv, hbA, e0, e1, Wr2_o, 512, 256, hbuf /*hs*/, hv, nullptr, A_v);
    }

    // ---- layer 2 node side ----
    rowgemm_k<128, 128, 0><<<cdiv(NN, 64), 256, 0, stream>>>(
        A_s, 128, Wlin2_s, 128, A_s, 128, NN, inv16);
    rowgemm_k<128, 128, 0><<<cdiv(3 * NN, 64), 256, 0, stream>>>(
        A_v, 128, Wlin2_v, 128, A_v, 128, 3 * NN, inv16);
    k_sc<<<NN, 128, 0, stream>>>(species, h_v, Wsk, h2v);
    k_B2<<<cdiv(NN * CC, 256), 256, 0, stream>>>(species, A_s, A_v, P2_v1, P2_sv, A_v /*B2v*/);
    rowgemm_k<128, 128, 6><<<cdiv(3 * NN, 64), 256, 0, stream>>>(
        A_v /*B2v*/, 128, Lp2_v, 128, h2v, 128, 3 * NN, one);

    k_node_out<<<NN, 64, 0, stream>>>(h2v, rmix, dip1, charges, positions, out, tot);
    k_greduce<<<NGR, 256, 0, stream>>>(tot, batch, out);
}

// Round 4
// 1217.402 us; speedup vs baseline: 6.2498x; 1.0148x over previous
//
#include <hip/hip_runtime.h>

#define NN 10000
#define EE 160000
#define CC 128
#define NEL 10
#define NGR 16

static inline int cdiv(int a, int b) { return (a + b - 1) / b; }

__device__ __forceinline__ float silu_f(float x) { return x / (1.0f + __expf(-x)); }

// ---------------------------------------------------------------------------
// Generic row-GEMM: out[r][c] = sum_k in[r][k] * W[k][c]   (W row-major, w_ld)
// MODE 0: store   1: store+silu   6: out += (accumulate)
// ---------------------------------------------------------------------------
template <int K, int N, int MODE>
__global__ __launch_bounds__(256) void rowgemm_k(
    const float* __restrict__ in, int in_ld,
    const float* __restrict__ W, int w_ld,
    float* __restrict__ out, int out_ld,
    int R, float scale)
{
    constexpr int TR = 8192 / N;
    constexpr int CG = N / 8;
    constexpr int RG = 256 / CG;
    static_assert(RG * 4 == TR, "tile shape mismatch");
    constexpr int KC = (K < 64 ? K : 64);

    __shared__ float Wl[KC][N];
    __shared__ float inT[K][TR + 4];

    const int tid = threadIdx.x;
    const int cg = tid % CG, rg = tid / CG;
    const int c0 = cg * 8, r0 = rg * 4;
    const int row0 = blockIdx.x * TR;

    for (int i = tid; i < K * TR; i += 256) {
        int r = i / K, k = i - r * K;
        int row = row0 + r;
        inT[k][r] = (row < R) ? in[row * in_ld + k] : 0.0f;
    }

    float acc[4][8];
#pragma unroll
    for (int i = 0; i < 4; ++i)
#pragma unroll
        for (int j = 0; j < 8; ++j) acc[i][j] = 0.0f;

    for (int kc = 0; kc < K; kc += KC) {
        __syncthreads();
        for (int i = tid; i < KC * N; i += 256) {
            int k = i / N, c = i - k * N;
            Wl[k][c] = W[(kc + k) * w_ld + c];
        }
        __syncthreads();
#pragma unroll 8
        for (int kk = 0; kk < KC; ++kk) {
            const float4 a  = *(const float4*)&inT[kc + kk][r0];
            const float4 b0 = *(const float4*)&Wl[kk][c0];
            const float4 b1 = *(const float4*)&Wl[kk][c0 + 4];
            const float av[4] = {a.x, a.y, a.z, a.w};
            const float bv[8] = {b0.x, b0.y, b0.z, b0.w, b1.x, b1.y, b1.z, b1.w};
#pragma unroll
            for (int i = 0; i < 4; ++i)
#pragma unroll
                for (int j = 0; j < 8; ++j)
                    acc[i][j] = fmaf(av[i], bv[j], acc[i][j]);
        }
    }

#pragma unroll
    for (int i = 0; i < 4; ++i) {
        int row = row0 + r0 + i;
        if (row >= R) break;
#pragma unroll
        for (int j = 0; j < 8; ++j) {
            float v = acc[i][j] * scale;
            if constexpr (MODE == 1) v = silu_f(v);
            int idx = row * out_ld + c0 + j;
            if constexpr (MODE == 6) out[idx] += v;
            else out[idx] = v;
        }
    }
}

// ---------------------------------------------------------------------------
// CSR build
// ---------------------------------------------------------------------------
__global__ void k_count(const int* __restrict__ rcv, int* __restrict__ deg)
{
    int e = blockIdx.x * 256 + threadIdx.x;
    if (e < EE) atomicAdd(&deg[rcv[e]], 1);
}

__global__ __launch_bounds__(256) void k_scan(const int* __restrict__ deg,
                                              int* __restrict__ rowptr,
                                              int* __restrict__ cursor)
{
    __shared__ int part[256];
    const int t = threadIdx.x;
    const int PER = (NN + 255) / 256;   // 40
    int base = t * PER;
    int s = 0;
    for (int j = 0; j < PER; ++j) { int idx = base + j; if (idx < NN) s += deg[idx]; }
    part[t] = s;
    __syncthreads();
    for (int off = 1; off < 256; off <<= 1) {
        int v = (t >= off) ? part[t - off] : 0;
        __syncthreads();
        part[t] += v;
        __syncthreads();
    }
    int run = (t == 0) ? 0 : part[t - 1];
    for (int j = 0; j < PER; ++j) {
        int idx = base + j;
        if (idx < NN) { rowptr[idx] = run; cursor[idx] = run; run += deg[idx]; }
    }
    if (t == 255) rowptr[NN] = part[255];
}

__global__ void k_fill(const int* __restrict__ rcv, int* __restrict__ cursor,
                       int* __restrict__ perm)
{
    int e = blockIdx.x * 256 + threadIdx.x;
    if (e >= EE) return;
    int pos = atomicAdd(&cursor[rcv[e]], 1);
    perm[pos] = e;
}

__global__ void k_sortseg(const int* __restrict__ rowptr, int* __restrict__ perm)
{
    int n = blockIdx.x * 256 + threadIdx.x;
    if (n >= NN) return;
    int a = rowptr[n], b = rowptr[n + 1];
    for (int i = a + 1; i < b; ++i) {
        int v = perm[i];
        int j = i - 1;
        while (j >= a && perm[j] > v) { perm[j + 1] = perm[j]; --j; }
        perm[j + 1] = v;
    }
}

// geometry, written in CSR (permuted) edge order
__global__ void k_geom_perm(const float* __restrict__ pos, const float* __restrict__ shifts,
                            const int* __restrict__ snd, const int* __restrict__ rcv,
                            const int* __restrict__ perm,
                            float* __restrict__ Yv, float* __restrict__ ef,
                            int* __restrict__ psnd)
{
    int i = blockIdx.x * 256 + threadIdx.x;
    if (i >= EE) return;
    int e = perm[i];
    int s = snd[e], r = rcv[e];
    psnd[i] = s;
    float vx = pos[r * 3 + 0] - pos[s * 3 + 0] + shifts[e * 3 + 0];
    float vy = pos[r * 3 + 1] - pos[s * 3 + 1] + shifts[e * 3 + 1];
    float vz = pos[r * 3 + 2] - pos[s * 3 + 2] + shifts[e * 3 + 2];
    float len = sqrtf(vx * vx + vy * vy + vz * vz + 1e-12f);
    float inv = 1.0f / len;
    const float SQ3 = 1.7320508075688772f;
    Yv[i * 3 + 0] = SQ3 * vx * inv;
    Yv[i * 3 + 1] = SQ3 * vy * inv;
    Yv[i * 3 + 2] = SQ3 * vz * inv;
    float u = len * 0.2f;
    float fc = 0.0f;
    if (u < 1.0f) {
        float u2 = u * u, u4 = u2 * u2, u5 = u4 * u, u6 = u5 * u, u7 = u6 * u;
        fc = 1.0f - 21.0f * u5 + 35.0f * u6 - 15.0f * u7;
    }
    float pref = 0.6324555320336759f * inv * fc;
    const float PIO5 = 0.6283185307179586f;
#pragma unroll
    for (int n = 1; n <= 8; ++n)
        ef[i * 8 + n - 1] = pref * sinf((float)n * PIO5 * len);
}

// ---------------------------------------------------------------------------
// Fused output-layer GEMM + segment gather (owner-computes, no atomics).
// Dot product uses 4 independent accumulators (breaks the 64-deep dependent
// FMA chain that capped VALUBusy at 32%).
// ---------------------------------------------------------------------------
template <int MG>
__global__ __launch_bounds__(256) void k_gather(
    const int* __restrict__ rowptr, const int* __restrict__ psnd,
    const float* __restrict__ Yv, const float* __restrict__ hb, int e0, int e1,
    const float* __restrict__ W, int wld, int coloff,
    const float* __restrict__ gS, const float* __restrict__ gV,
    float* __restrict__ outS, float* __restrict__ outV)
{
    constexpr int NPB = 8;
    __shared__ float red[256 * 3];
    const int t = threadIdx.x;
    const int c = t & 127;
    const int hi = t >> 7;
    const int n0 = blockIdx.x * NPB;

    const int wcol = coloff + ((MG == 1) ? t : hi * 128 + c);
    float wreg[64];
#pragma unroll
    for (int k = 0; k < 64; ++k) wreg[k] = W[k * wld + wcol];

    for (int n = n0; n < n0 + NPB; ++n) {
        int rs = rowptr[n], re = rowptr[n + 1];
        if (rs < e0) rs = e0;
        if (re > e1) re = e1;
        float accs = 0.0f, a0 = 0.0f, a1 = 0.0f, a2 = 0.0f;
        for (int i = rs; i < re; ++i) {
            const float4* hp4 = (const float4*)(hb + (size_t)(i - e0) * 64);
            // 4-way ILP dot product (chain depth 16 instead of 64)
            float d0 = 0.f, d1 = 0.f, d2 = 0.f, d3 = 0.f;
#pragma unroll
            for (int k = 0; k < 16; ++k) {
                float4 h = hp4[k];
                d0 = fmaf(h.x, wreg[4 * k + 0], d0);
                d1 = fmaf(h.y, wreg[4 * k + 1], d1);
                d2 = fmaf(h.z, wreg[4 * k + 2], d2);
                d3 = fmaf(h.w, wreg[4 * k + 3], d3);
            }
            const float w = (d0 + d1) + (d2 + d3);
            const int s = psnd[i];
            if constexpr (MG == 1) {
                float hv_ = gS[s * 128 + c];
                if (hi == 0) {
                    accs = fmaf(w, hv_, accs);
                } else {
                    float tv = w * hv_;
                    float y0 = Yv[i * 3], y1 = Yv[i * 3 + 1], y2 = Yv[i * 3 + 2];
                    a0 = fmaf(tv, y0, a0); a1 = fmaf(tv, y1, a1); a2 = fmaf(tv, y2, a2);
                }
            } else if constexpr (MG == 2) {
                if (hi == 0) {
                    accs = fmaf(w, gS[s * 128 + c], accs);
                } else {
                    float y0 = Yv[i * 3], y1 = Yv[i * 3 + 1], y2 = Yv[i * 3 + 2];
                    float hd = gV[s * 384 + c] * y0 + gV[s * 384 + 128 + c] * y1
                             + gV[s * 384 + 256 + c] * y2;
                    accs = fmaf(w, hd * 0.57735026919f, accs);
                }
            } else {
                if (hi == 0) {
                    float tv = w * gS[s * 128 + c];
                    float y0 = Yv[i * 3], y1 = Yv[i * 3 + 1], y2 = Yv[i * 3 + 2];
                    a0 = fmaf(tv, y0, a0); a1 = fmaf(tv, y1, a1); a2 = fmaf(tv, y2, a2);
                } else {
                    a0 = fmaf(w, gV[s * 384 + c], a0);
                    a1 = fmaf(w, gV[s * 384 + 128 + c], a1);
                    a2 = fmaf(w, gV[s * 384 + 256 + c], a2);
                }
            }
        }
        // epilogue (no atomics: this block exclusively owns node n)
        if constexpr (MG == 1) {
            if (hi == 0) {
                outS[n * 128 + c] += accs;
            } else {
                outV[n * 384 + c]       += a0;
                outV[n * 384 + 128 + c] += a1;
                outV[n * 384 + 256 + c] += a2;
            }
        } else if constexpr (MG == 2) {
            red[t] = accs;
            __syncthreads();
            if (hi == 0) outS[n * 128 + c] += red[c] + red[128 + c];
            __syncthreads();
        } else {
            red[t * 3] = a0; red[t * 3 + 1] = a1; red[t * 3 + 2] = a2;
            __syncthreads();
            if (hi == 0) {
                outV[n * 384 + c]       += a0 + red[(128 + c) * 3];
                outV[n * 384 + 128 + c] += a1 + red[(128 + c) * 3 + 1];
                outV[n * 384 + 256 + c] += a2 + red[(128 + c) * 3 + 2];
            }
            __syncthreads();
        }
    }
}

// ---------------------------------------------------------------------------
__global__ void k_species(const float* __restrict__ attrs, int* __restrict__ species)
{
    int n = blockIdx.x * 256 + threadIdx.x;
    if (n >= NN) return;
    int sp = 0;
#pragma unroll
    for (int j = 0; j < NEL; ++j)
        if (attrs[n * NEL + j] > 0.5f) sp = j;
    species[n] = sp;
}

__global__ void k_embed(const float* __restrict__ W_emb, const int* __restrict__ species,
                        float* __restrict__ h)
{
    int t = blockIdx.x * 256 + threadIdx.x;
    if (t >= NN * CC) return;
    int n = t >> 7, c = t & 127;
    h[t] = W_emb[species[n] * CC + c];
}

__global__ void k_rmix(const float* __restrict__ Rmid, const float* __restrict__ Rout,
                       float* __restrict__ rmix)
{
    int c = threadIdx.x;
    float s = 0.f;
#pragma unroll
    for (int k = 0; k < 16; ++k) s = fmaf(Rmid[c * 16 + k], Rout[k], s);
    rmix[c] = s;
}

__global__ void k_B1(const int* __restrict__ species,
                     const float* __restrict__ As_l, const float* __restrict__ Av_l,
                     const float* __restrict__ P_s1, const float* __restrict__ P_ss,
                     const float* __restrict__ P_vv, const float* __restrict__ P_v1,
                     const float* __restrict__ P_sv,
                     float* __restrict__ Bs, float* __restrict__ Bv)
{
    int t = blockIdx.x * 256 + threadIdx.x;
    if (t >= NN * CC) return;
    int n = t >> 7, c = t & 127;
    int sp = species[n];
    int pb = sp * CC + c;
    int vb = n * 384 + c;
    float as = As_l[t];
    float a0 = Av_l[vb], a1 = Av_l[vb + CC], a2 = Av_l[vb + 2 * CC];
    Bs[t] = P_s1[pb] * as + P_ss[pb] * as * as
          + P_vv[pb] * (a0 * a0 + a1 * a1 + a2 * a2) * 0.57735026919f;
    float tv = P_v1[pb] + P_sv[pb] * as;
    Bv[vb] = tv * a0; Bv[vb + CC] = tv * a1; Bv[vb + 2 * CC] = tv * a2;
}

__global__ void k_B2(const int* __restrict__ species,
                     const float* __restrict__ As_l, const float* __restrict__ Av_l,
                     const float* __restrict__ P_v1, const float* __restrict__ P_sv,
                     float* __restrict__ Bv)
{
    int t = blockIdx.x * 256 + threadIdx.x;
    if (t >= NN * CC) return;
    int n = t >> 7, c = t & 127;
    int sp = species[n];
    int pb = sp * CC + c;
    int vb = n * 384 + c;
    float as = As_l[t];
    float tv = P_v1[pb] + P_sv[pb] * as;
    Bv[vb] = tv * Av_l[vb];
    Bv[vb + CC] = tv * Av_l[vb + CC];
    Bv[vb + 2 * CC] = tv * Av_l[vb + 2 * CC];
}

__global__ void k_dip1(const float* __restrict__ h_v, const float* __restrict__ R1,
                       float* __restrict__ dip1)
{
    int n = blockIdx.x, l = threadIdx.x;
    const float* hb = h_v + n * 384;
#pragma unroll
    for (int d = 0; d < 3; ++d) {
        float v = hb[d * CC + l] * R1[l] + hb[d * CC + 64 + l] * R1[64 + l];
        for (int o = 32; o > 0; o >>= 1) v += __shfl_down(v, o);
        if (l == 0) dip1[n * 3 + d] = v;
    }
}

__global__ void k_sc(const int* __restrict__ species, const float* __restrict__ h_v,
                     const float* __restrict__ Wsk, float* __restrict__ h2v)
{
    int n = blockIdx.x, f = threadIdx.x;
    int sp = species[n];
    const float* Wp = Wsk + sp * (CC * CC);
    const float* hvn = h_v + n * 384;
    float a0 = 0.f, a1 = 0.f, a2 = 0.f;
    for (int c = 0; c < CC; ++c) {
        float w = Wp[c * CC + f];
        a0 = fmaf(hvn[c], w, a0);
        a1 = fmaf(hvn[CC + c], w, a1);
        a2 = fmaf(hvn[2 * CC + c], w, a2);
    }
    h2v[n * 384 + f] = a0;
    h2v[n * 384 + CC + f] = a1;
    h2v[n * 384 + 2 * CC + f] = a2;
}

// per-node output: atomic dipole -> out[48+...], graph contribution -> tot[n][3]
__global__ void k_node_out(const float* __restrict__ h2v, const float* __restrict__ rmix,
                           const float* __restrict__ dip1,
                           const float* __restrict__ charges, const float* __restrict__ pos,
                           float* __restrict__ out, float* __restrict__ tot)
{
    int n = blockIdx.x, l = threadIdx.x;
    const float* hb = h2v + n * 384;
    float r0 = rmix[l], r1 = rmix[64 + l];
    float red[3];
#pragma unroll
    for (int d = 0; d < 3; ++d) {
        float v = hb[d * CC + l] * r0 + hb[d * CC + 64 + l] * r1;
        for (int o = 32; o > 0; o >>= 1) v += __shfl_down(v, o);
        red[d] = v;
    }
    if (l == 0) {
        float q = charges[n];
#pragma unroll
        for (int d = 0; d < 3; ++d) {
            float a = dip1[n * 3 + d] + 0.5f * red[d];
            out[48 + n * 3 + d] = a;
            tot[n * 3 + d] = a + q * pos[n * 3 + d];
        }
    }
}

// graph totals: one block per graph, no atomics
__global__ __launch_bounds__(256) void k_greduce(const float* __restrict__ tot,
                                                 const int* __restrict__ batch,
                                                 float* __restrict__ out)
{
    __shared__ float r[256 * 3];
    const int g = blockIdx.x;
    const int t = threadIdx.x;
    float s0 = 0.f, s1 = 0.f, s2 = 0.f;
    for (int n = t; n < NN; n += 256) {
        if (batch[n] == g) {
            s0 += tot[n * 3]; s1 += tot[n * 3 + 1]; s2 += tot[n * 3 + 2];
        }
    }
    r[t] = s0; r[256 + t] = s1; r[512 + t] = s2;
    __syncthreads();
    for (int off = 128; off > 0; off >>= 1) {
        if (t < off) {
            r[t] += r[t + off];
            r[256 + t] += r[256 + t + off];
            r[512 + t] += r[512 + t + off];
        }
        __syncthreads();
    }
    if (t < 3) out[g * 3 + t] = r[t * 256];
}

// ---------------------------------------------------------------------------
extern "C" void kernel_launch(void* const* d_in, const int* in_sizes, int n_in,
                              void* d_out, int out_size, void* d_ws, size_t ws_size,
                              hipStream_t stream)
{
    const float* positions = (const float*)d_in[0];
    const float* node_attrs = (const float*)d_in[1];
    const float* charges = (const float*)d_in[2];
    const float* shifts = (const float*)d_in[3];
    const int*   eidx = (const int*)d_in[4];
    const int*   batch = (const int*)d_in[5];
    const float* W_emb  = (const float*)d_in[7];
    const float* W_up1  = (const float*)d_in[8];
    const float* Wr1_1  = (const float*)d_in[9];
    const float* Wr1_2  = (const float*)d_in[10];
    const float* Wr1_3  = (const float*)d_in[11];
    const float* Wr1_o  = (const float*)d_in[12];
    const float* Wlin1_s = (const float*)d_in[13];
    const float* Wlin1_v = (const float*)d_in[14];
    const float* P1_s1 = (const float*)d_in[15];
    const float* P1_ss = (const float*)d_in[16];
    const float* P1_vv = (const float*)d_in[17];
    const float* P1_v1 = (const float*)d_in[18];
    const float* P1_sv = (const float*)d_in[19];
    const float* Lp1_s = (const float*)d_in[20];
    const float* Lp1_v = (const float*)d_in[21];
    const float* R1    = (const float*)d_in[22];
    const float* Wsk   = (const float*)d_in[23];
    const float* Wup2_s = (const float*)d_in[24];
    const float* Wup2_v = (const float*)d_in[25];
    const float* Wr2_1 = (const float*)d_in[26];
    const float* Wr2_2 = (const float*)d_in[27];
    const float* Wr2_3 = (const float*)d_in[28];
    const float* Wr2_o = (const float*)d_in[29];
    const float* Wlin2_s = (const float*)d_in[30];
    const float* Wlin2_v = (const float*)d_in[31];
    const float* P2_v1 = (const float*)d_in[32];
    const float* P2_sv = (const float*)d_in[33];
    const float* Lp2_v = (const float*)d_in[34];
    const float* Rmid  = (const float*)d_in[35];
    const float* Rout  = (const float*)d_in[36];
    (void)in_sizes; (void)n_in; (void)out_size;

    const int* snd = eidx;
    const int* rcv = eidx + EE;
    float* out = (float*)d_out;

    const int NCH  = (ws_size >= (size_t)175 * 1024 * 1024) ? 1 : 2;
    const int ECHn = EE / NCH;

    char* ws = (char*)d_ws;
    size_t off = 0;
    auto alloc = [&](size_t bytes) -> float* {
        float* p = (float*)(ws + off);
        off = (off + bytes + 255) & ~(size_t)255;
        return p;
    };
    int*   species = (int*)alloc((size_t)NN * 4);
    int*   deg     = (int*)alloc((size_t)NN * 4);
    int*   rowptr  = (int*)alloc((size_t)(NN + 16) * 4);
    int*   cursor  = (int*)alloc((size_t)NN * 4);
    int*   perm    = (int*)alloc((size_t)EE * 4);
    int*   psnd    = (int*)alloc((size_t)EE * 4);
    float* Yv   = alloc((size_t)EE * 3 * 4);
    float* ef   = alloc((size_t)EE * 8 * 4);
    float* A_s  = alloc((size_t)NN * CC * 4);       // A_s / As_l (in place); A2_s
    float* A_v  = alloc((size_t)NN * 3 * CC * 4);   // A_v / Av_l / Bv / A2_v / B2v
    float* hbuf = alloc((size_t)NN * CC * 4);       // h -> Bs -> hs
    float* hu   = alloc((size_t)NN * CC * 4);       // hu -> h_s
    float* h_v  = alloc((size_t)NN * 3 * CC * 4);   // layer-1 vector feats (kept for sc_v)
    float* hv   = alloc((size_t)NN * 3 * CC * 4);
    float* h2v  = alloc((size_t)NN * 3 * CC * 4);
    float* dip1 = alloc((size_t)NN * 3 * 4);
    float* rmix = alloc((size_t)CC * 4);
    float* tot  = alloc((size_t)NN * 3 * 4);
    float* hbA  = alloc((size_t)ECHn * 64 * 4);
    float* hbB  = alloc((size_t)ECHn * 64 * 4);

    const float inv16 = 1.0f / 16.0f;
    const float one = 1.0f;

    hipMemsetAsync(deg, 0, (size_t)NN * 4, stream);
    hipMemsetAsync(A_s, 0, (size_t)NN * CC * 4, stream);
    hipMemsetAsync(A_v, 0, (size_t)NN * 3 * CC * 4, stream);

    // ---- CSR build + permuted geometry ----
    k_count<<<cdiv(EE, 256), 256, 0, stream>>>(rcv, deg);
    k_scan<<<1, 256, 0, stream>>>(deg, rowptr, cursor);
    k_fill<<<cdiv(EE, 256), 256, 0, stream>>>(rcv, cursor, perm);
    k_sortseg<<<cdiv(NN, 256), 256, 0, stream>>>(rowptr, perm);
    k_geom_perm<<<cdiv(EE, 256), 256, 0, stream>>>(positions, shifts, snd, rcv, perm, Yv, ef, psnd);

    k_species<<<cdiv(NN, 256), 256, 0, stream>>>(node_attrs, species);
    k_embed<<<cdiv(NN * CC, 256), 256, 0, stream>>>(W_emb, species, hbuf);
    k_rmix<<<1, CC, 0, stream>>>(Rmid, Rout, rmix);

    // hu = h @ W_up1
    rowgemm_k<128, 128, 0><<<cdiv(NN, 64), 256, 0, stream>>>(
        hbuf, 128, W_up1, 128, hu, 128, NN, one);

    // ---- layer 1: edge MLP + fused gather ----
    for (int ch = 0; ch < NCH; ++ch) {
        int e0 = ch * ECHn, e1 = e0 + ECHn;
        rowgemm_k<8, 64, 1><<<cdiv(ECHn, 128), 256, 0, stream>>>(
            ef + (size_t)e0 * 8, 8, Wr1_1, 64, hbA, 64, ECHn, one);
        rowgemm_k<64, 64, 1><<<cdiv(ECHn, 128), 256, 0, stream>>>(
            hbA, 64, Wr1_2, 64, hbB, 64, ECHn, one);
        rowgemm_k<64, 64, 1><<<cdiv(ECHn, 128), 256, 0, stream>>>(
            hbB, 64, Wr1_3, 64, hbA, 64, ECHn, one);
        k_gather<1><<<NN / 8, 256, 0, stream>>>(
            rowptr, psnd, Yv, hbA, e0, e1, Wr1_o, 256, 0, hu, nullptr, A_s, A_v);
    }

    // ---- layer 1 node side (Wlin in place) ----
    rowgemm_k<128, 128, 0><<<cdiv(NN, 64), 256, 0, stream>>>(
        A_s, 128, Wlin1_s, 128, A_s, 128, NN, inv16);
    rowgemm_k<128, 128, 0><<<cdiv(3 * NN, 64), 256, 0, stream>>>(
        A_v, 128, Wlin1_v, 128, A_v, 128, 3 * NN, inv16);
    k_B1<<<cdiv(NN * CC, 256), 256, 0, stream>>>(
        species, A_s, A_v, P1_s1, P1_ss, P1_vv, P1_v1, P1_sv, hbuf /*Bs*/, A_v /*Bv*/);
    rowgemm_k<128, 128, 0><<<cdiv(NN, 64), 256, 0, stream>>>(
        hbuf, 128, Lp1_s, 128, hu /*h_s*/, 128, NN, one);
    rowgemm_k<128, 128, 0><<<cdiv(3 * NN, 64), 256, 0, stream>>>(
        A_v /*Bv*/, 128, Lp1_v, 128, h_v, 128, 3 * NN, one);
    k_dip1<<<NN, 64, 0, stream>>>(h_v, R1, dip1);
    rowgemm_k<128, 128, 0><<<cdiv(NN, 64), 256, 0, stream>>>(
        hu /*h_s*/, 128, Wup2_s, 128, hbuf /*hs*/, 128, NN, one);
    rowgemm_k<128, 128, 0><<<cdiv(3 * NN, 64), 256, 0, stream>>>(
        h_v, 128, Wup2_v, 128, hv, 128, 3 * NN, one);

    // ---- layer 2: edge MLP + fused gathers ----
    hipMemsetAsync(A_s, 0, (size_t)NN * CC * 4, stream);
    hipMemsetAsync(A_v, 0, (size_t)NN * 3 * CC * 4, stream);
    for (int ch = 0; ch < NCH; ++ch) {
        int e0 = ch * ECHn, e1 = e0 + ECHn;
        rowgemm_k<8, 64, 1><<<cdiv(ECHn, 128), 256, 0, stream>>>(
            ef + (size_t)e0 * 8, 8, Wr2_1, 64, hbA, 64, ECHn, one);
        rowgemm_k<64, 64, 1><<<cdiv(ECHn, 128), 256, 0, stream>>>(
            hbA, 64, Wr2_2, 64, hbB, 64, ECHn, one);
        rowgemm_k<64, 64, 1><<<cdiv(ECHn, 128), 256, 0, stream>>>(
            hbB, 64, Wr2_3, 64, hbA, 64, ECHn, one);
        k_gather<2><<<NN / 8, 256, 0, stream>>>(
            rowptr, psnd, Yv, hbA, e0, e1, Wr2_o, 512, 0, hbuf /*hs*/, hv, A_s, nullptr);
        k_gather<3><<<NN / 8, 256, 0, stream>>>(
            rowptr, psnd, Yv, hbA, e0, e1, Wr2_o, 512, 256, hbuf /*hs*/, hv, nullptr, A_v);
    }

    // ---- layer 2 node side ----
    rowgemm_k<128, 128, 0><<<cdiv(NN, 64), 256, 0, stream>>>(
        A_s, 128, Wlin2_s, 128, A_s, 128, NN, inv16);
    rowgemm_k<128, 128, 0><<<cdiv(3 * NN, 64), 256, 0, stream>>>(
        A_v, 128, Wlin2_v, 128, A_v, 128, 3 * NN, inv16);
    k_sc<<<NN, 128, 0, stream>>>(species, h_v, Wsk, h2v);
    k_B2<<<cdiv(NN * CC, 256), 256, 0, stream>>>(species, A_s, A_v, P2_v1, P2_sv, A_v /*B2v*/);
    rowgemm_k<128, 128, 6><<<cdiv(3 * NN, 64), 256, 0, stream>>>(
        A_v /*B2v*/, 128, Lp2_v, 128, h2v, 128, 3 * NN, one);

    k_node_out<<<NN, 64, 0, stream>>>(h2v, rmix, dip1, charges, positions, out, tot);
    k_greduce<<<NGR, 256, 0, stream>>>(tot, batch, out);
}